// Round 2
// 1242.687 us; speedup vs baseline: 1.0500x; 1.0500x over previous
//
#include <hip/hip_runtime.h>
#include <hip/hip_bf16.h>

typedef unsigned short u16;
typedef unsigned int u32;
typedef __bf16 bf16x8 __attribute__((ext_vector_type(8)));
typedef float f32x4 __attribute__((ext_vector_type(4)));
typedef unsigned int u32x4 __attribute__((ext_vector_type(4)));
typedef unsigned int u32x2 __attribute__((ext_vector_type(2)));

#define TXT 512
#define SEQ 2048
#define STOT 2560
#define DIM 3072
#define NH 24
#define HD 128
#define SOFTMAX_SCALE 0.08838834764831845f

__device__ __forceinline__ float b2f(u16 u) {
    union { u32 i; float f; } c; c.i = ((u32)u) << 16; return c.f;
}
__device__ __forceinline__ u16 f2b(float f) {
    union { float f; u32 i; } c; c.f = f;
    u32 x = c.i;
    return (u16)((x + 0x7FFFu + ((x >> 16) & 1u)) >> 16);
}
__device__ __forceinline__ u32 pk2(float a, float b) {
    __hip_bfloat162 h = __float22bfloat162_rn(make_float2(a, b));
    return *reinterpret_cast<u32*>(&h);
}
__device__ __forceinline__ f32x4 max4(f32x4 a, f32x4 b) {
    return (f32x4){fmaxf(a[0], b[0]), fmaxf(a[1], b[1]),
                   fmaxf(a[2], b[2]), fmaxf(a[3], b[3])};
}
__device__ __forceinline__ f32x4 shfl_xor4(f32x4 v, int mask) {
    return (f32x4){__shfl_xor(v[0], mask), __shfl_xor(v[1], mask),
                   __shfl_xor(v[2], mask), __shfl_xor(v[3], mask)};
}

// ---------------------------------------------------------------------------
// transpose_w: W fp32 [K][Ntot] -> WT bf16 [ncols][K] (ncols from nbase).
// ---------------------------------------------------------------------------
__global__ __launch_bounds__(256, 2) void transpose_w_kernel(
    const float* __restrict__ W, u16* __restrict__ WT,
    int K, int Ntot, int nbase)
{
    __shared__ u16 Ts[64][66];
    const int t   = threadIdx.x;
    const int k0  = blockIdx.x * 64;
    const int n0l = blockIdx.y * 64;
    const int n0g = nbase + n0l;

    {
        const int krow = t >> 2;
        const int nseg = (t & 3) * 16;
        const float* src = &W[(size_t)(k0 + krow) * Ntot + n0g + nseg];
        f32x4 v0 = reinterpret_cast<const f32x4*>(src)[0];
        f32x4 v1 = reinterpret_cast<const f32x4*>(src)[1];
        f32x4 v2 = reinterpret_cast<const f32x4*>(src)[2];
        f32x4 v3 = reinterpret_cast<const f32x4*>(src)[3];
        #pragma unroll
        for (int i = 0; i < 4; i++) Ts[nseg +      i][krow] = f2b(v0[i]);
        #pragma unroll
        for (int i = 0; i < 4; i++) Ts[nseg +  4 + i][krow] = f2b(v1[i]);
        #pragma unroll
        for (int i = 0; i < 4; i++) Ts[nseg +  8 + i][krow] = f2b(v2[i]);
        #pragma unroll
        for (int i = 0; i < 4; i++) Ts[nseg + 12 + i][krow] = f2b(v3[i]);
    }
    __syncthreads();
    {
        const int nrow = t >> 2;
        const int kseg = (t & 3) * 16;
        u32 out[8];
        #pragma unroll
        for (int c = 0; c < 8; c++)
            out[c] = (u32)Ts[nrow][kseg + 2 * c] | ((u32)Ts[nrow][kseg + 2 * c + 1] << 16);
        u16* dst = &WT[(size_t)(n0l + nrow) * K + k0 + kseg];
        *reinterpret_cast<u32x4*>(dst)     = (u32x4){out[0], out[1], out[2], out[3]};
        *reinterpret_cast<u32x4*>(dst + 8) = (u32x4){out[4], out[5], out[6], out[7]};
    }
}

// ---------------------------------------------------------------------------
// gemm_bt: C = A[M,K] @ B + bias, BT bf16 [ncols][K] pre-transposed.
// BK=64 (32 MFMA between barriers). MT = M-tile (128 or 64; 64 doubles the
// grid for M=512 shapes -> better CU coverage). 4 waves as 2x2; wave tile
// (MT/2) x 64. AF32: A fp32 (pk2-converted) else bf16.
// OUTMODE: 0 bf16 row-major, 1 fp32 row-major, 2 bf16 transposed VT[N][STOT].
// ---------------------------------------------------------------------------
template<int AF32, int OUTMODE, int MT>
__global__ __launch_bounds__(256, 2) void gemm_bt_kernel(
    const void* __restrict__ Av, const u16* __restrict__ BT,
    const float* __restrict__ bias, void* __restrict__ Cv, size_t coff,
    int M, int K, int Ntot, int ncol0)
{
    constexpr int MI = MT / 32;            // acc row-tiles per wave
    constexpr int ASEGN = (MT == 128) ? 32 : 16;  // A k-elems staged/thread
    __shared__ u16 As[MT][72];             // [m][k], +8 pad
    __shared__ u16 Bs[128][72];            // [n][k], +8 pad

    const int t    = threadIdx.x;
    const int lane = t & 63;
    const int wave = t >> 6;
    const int wr   = wave >> 1;
    const int wc   = wave & 1;
    const int m0   = blockIdx.x * MT;
    const int n0   = blockIdx.y * 128;
    const int fm   = lane & 15;
    const int fq   = lane >> 4;

    const int arow = (MT == 128) ? (t >> 1) : (t >> 2);
    const int aseg = (MT == 128) ? ((t & 1) * 32) : ((t & 3) * 16);
    const int brow = t >> 1;
    const int bseg = (t & 1) * 32;

    f32x4 acc[MI][4];
    #pragma unroll
    for (int i = 0; i < MI; i++)
        #pragma unroll
        for (int j = 0; j < 4; j++)
            acc[i][j] = (f32x4){0.f, 0.f, 0.f, 0.f};

    for (int k0 = 0; k0 < K; k0 += 64) {
        // ---- A fragment: ASEGN consecutive k ----
        u32 aw[ASEGN / 2];
        if (AF32) {
            const float* ap = (const float*)Av + (size_t)(m0 + arow) * K + k0 + aseg;
            #pragma unroll
            for (int c = 0; c < ASEGN / 4; c++) {
                f32x4 x = reinterpret_cast<const f32x4*>(ap)[c];
                aw[2 * c]     = pk2(x[0], x[1]);
                aw[2 * c + 1] = pk2(x[2], x[3]);
            }
        } else {
            const u32x4* ap = reinterpret_cast<const u32x4*>(
                (const u16*)Av + (size_t)(m0 + arow) * K + k0 + aseg);
            #pragma unroll
            for (int c = 0; c < ASEGN / 8; c++) {
                u32x4 x = ap[c];
                aw[4 * c] = x[0]; aw[4 * c + 1] = x[1];
                aw[4 * c + 2] = x[2]; aw[4 * c + 3] = x[3];
            }
        }
        // ---- B fragment: 32 consecutive k (64 B) ----
        u32x4 bw[4];
        {
            const u32x4* bp = reinterpret_cast<const u32x4*>(
                &BT[(size_t)(n0 + brow) * K + k0 + bseg]);
            bw[0] = bp[0]; bw[1] = bp[1]; bw[2] = bp[2]; bw[3] = bp[3];
        }
        __syncthreads();   // prior iteration's LDS reads complete
        #pragma unroll
        for (int c = 0; c < ASEGN / 8; c++)
            *reinterpret_cast<u32x4*>(&As[arow][aseg + c * 8]) =
                (u32x4){aw[4 * c], aw[4 * c + 1], aw[4 * c + 2], aw[4 * c + 3]};
        #pragma unroll
        for (int c = 0; c < 4; c++)
            *reinterpret_cast<u32x4*>(&Bs[brow][bseg + c * 8]) = bw[c];
        __syncthreads();

        #pragma unroll
        for (int h = 0; h < 2; h++) {
            bf16x8 af[MI], bfr[4];
            #pragma unroll
            for (int i = 0; i < MI; i++)
                af[i] = *reinterpret_cast<const bf16x8*>(
                    &As[wr * (MT / 2) + i * 16 + fm][h * 32 + fq * 8]);
            #pragma unroll
            for (int j = 0; j < 4; j++)
                bfr[j] = *reinterpret_cast<const bf16x8*>(
                    &Bs[wc * 64 + j * 16 + fm][h * 32 + fq * 8]);
            #pragma unroll
            for (int i = 0; i < MI; i++)
                #pragma unroll
                for (int j = 0; j < 4; j++)
                    acc[i][j] = __builtin_amdgcn_mfma_f32_16x16x32_bf16(af[i], bfr[j], acc[i][j], 0, 0, 0);
        }
    }

    // epilogue: C/D layout col = lane&15, row = (lane>>4)*4 + r
    #pragma unroll
    for (int i = 0; i < MI; i++) {
        #pragma unroll
        for (int j = 0; j < 4; j++) {
            int col = ncol0 + n0 + wc * 64 + j * 16 + fm;
            float bb = bias[col];
            if (OUTMODE == 2) {
                int tok = (int)coff + m0 + wr * (MT / 2) + i * 16 + fq * 4;
                u32x2 pr = {pk2(acc[i][j][0] + bb, acc[i][j][1] + bb),
                            pk2(acc[i][j][2] + bb, acc[i][j][3] + bb)};
                *reinterpret_cast<u32x2*>(&((u16*)Cv)[(size_t)col * STOT + tok]) = pr;
            } else {
                #pragma unroll
                for (int r = 0; r < 4; r++) {
                    int row = m0 + wr * (MT / 2) + i * 16 + fq * 4 + r;
                    size_t idx = coff + (size_t)row * Ntot + col;
                    float val = acc[i][j][r] + bb;
                    if (OUTMODE == 1) ((float*)Cv)[idx] = val;
                    else              ((u16*)Cv)[idx]   = f2b(val);
                }
            }
        }
    }
}

// ---------------------------------------------------------------------------
// Fallback GEMM (fp32 W, scalar staging, BK=32) — only if ws too small.
// ---------------------------------------------------------------------------
template<int AF32, int OUTMODE>
__global__ __launch_bounds__(256, 2) void gemm_bias_kernel(
    const void* __restrict__ Av, const float* __restrict__ W,
    const float* __restrict__ bias, void* __restrict__ Cv, size_t coff,
    int M, int K, int N)
{
    __shared__ u16 As[128][40];
    __shared__ u16 Bs[128][40];

    const int t    = threadIdx.x;
    const int lane = t & 63;
    const int wave = t >> 6;
    const int wr   = wave >> 1;
    const int wc   = wave & 1;
    const int m0   = blockIdx.x * 128;
    const int n0   = blockIdx.y * 128;
    const int fm   = lane & 15;
    const int fq   = lane >> 4;

    const int arow = t >> 1;
    const int akg  = (t & 1) * 16;
    const int bn   = t >> 1;
    const int bkg  = (t & 1) * 16;

    f32x4 acc[4][4];
    #pragma unroll
    for (int i = 0; i < 4; i++)
        #pragma unroll
        for (int j = 0; j < 4; j++)
            acc[i][j] = (f32x4){0.f, 0.f, 0.f, 0.f};

    for (int k0 = 0; k0 < K; k0 += 32) {
        u32x4 a0, a1;
        if (AF32) {
            const f32x4* p = reinterpret_cast<const f32x4*>(
                (const float*)Av + (size_t)(m0 + arow) * K + k0 + akg);
            f32x4 x0 = p[0], x1 = p[1], x2 = p[2], x3 = p[3];
            a0 = (u32x4){pk2(x0[0], x0[1]), pk2(x0[2], x0[3]),
                         pk2(x1[0], x1[1]), pk2(x1[2], x1[3])};
            a1 = (u32x4){pk2(x2[0], x2[1]), pk2(x2[2], x2[3]),
                         pk2(x3[0], x3[1]), pk2(x3[2], x3[3])};
        } else {
            const u32x4* p = reinterpret_cast<const u32x4*>(
                (const u16*)Av + (size_t)(m0 + arow) * K + k0 + akg);
            a0 = p[0]; a1 = p[1];
        }
        float wv[16];
        #pragma unroll
        for (int j = 0; j < 16; j++)
            wv[j] = W[(size_t)(k0 + bkg + j) * N + n0 + bn];
        u32x4 b0, b1;
        #pragma unroll
        for (int j = 0; j < 4; j++) {
            b0[j] = pk2(wv[2 * j],     wv[2 * j + 1]);
            b1[j] = pk2(wv[8 + 2 * j], wv[8 + 2 * j + 1]);
        }
        __syncthreads();
        *reinterpret_cast<u32x4*>(&As[arow][akg])     = a0;
        *reinterpret_cast<u32x4*>(&As[arow][akg + 8]) = a1;
        *reinterpret_cast<u32x4*>(&Bs[bn][bkg])       = b0;
        *reinterpret_cast<u32x4*>(&Bs[bn][bkg + 8])   = b1;
        __syncthreads();

        bf16x8 af[4], bfr[4];
        #pragma unroll
        for (int i = 0; i < 4; i++)
            af[i] = *reinterpret_cast<const bf16x8*>(&As[wr * 64 + i * 16 + fm][fq * 8]);
        #pragma unroll
        for (int j = 0; j < 4; j++)
            bfr[j] = *reinterpret_cast<const bf16x8*>(&Bs[wc * 64 + j * 16 + fm][fq * 8]);
        #pragma unroll
        for (int i = 0; i < 4; i++)
            #pragma unroll
            for (int j = 0; j < 4; j++)
                acc[i][j] = __builtin_amdgcn_mfma_f32_16x16x32_bf16(af[i], bfr[j], acc[i][j], 0, 0, 0);
    }

    #pragma unroll
    for (int i = 0; i < 4; i++) {
        #pragma unroll
        for (int j = 0; j < 4; j++) {
            int col = n0 + wc * 64 + j * 16 + fm;
            float bb = bias[col];
            if (OUTMODE == 2) {
                int tok = (int)coff + m0 + wr * 64 + i * 16 + fq * 4;
                u32x2 pr = {pk2(acc[i][j][0] + bb, acc[i][j][1] + bb),
                            pk2(acc[i][j][2] + bb, acc[i][j][3] + bb)};
                *reinterpret_cast<u32x2*>(&((u16*)Cv)[(size_t)col * STOT + tok]) = pr;
            } else {
                #pragma unroll
                for (int r = 0; r < 4; r++) {
                    int row = m0 + wr * 64 + i * 16 + fq * 4 + r;
                    size_t idx = coff + (size_t)row * N + col;
                    float val = acc[i][j][r] + bb;
                    if (OUTMODE == 1) ((float*)Cv)[idx] = val;
                    else              ((u16*)Cv)[idx]   = f2b(val);
                }
            }
        }
    }
}

// ---------------------------------------------------------------------------
// Fused per-head RMSNorm + RoPE, in place. 4 waves/block, one token each.
// ---------------------------------------------------------------------------
__global__ __launch_bounds__(256) void rmsrope_kernel(
    u16* __restrict__ Qf, u16* __restrict__ Kf,
    const float* __restrict__ nq, const float* __restrict__ nk,
    const float* __restrict__ naq, const float* __restrict__ nak,
    const float* __restrict__ cosb, const float* __restrict__ sinb)
{
    const int h     = blockIdx.x;
    const int tok   = blockIdx.y * 4 + (threadIdx.x >> 6);
    const int which = blockIdx.z;
    u16* buf = which ? Kf : Qf;
    const float* nw = (tok < TXT) ? (which ? nak : naq) : (which ? nk : nq);
    const int t = threadIdx.x & 63;
    const size_t base = (size_t)tok * DIM + h * HD + 2 * t;

    u32 pr = *reinterpret_cast<const u32*>(&buf[base]);
    float x0 = b2f((u16)(pr & 0xFFFF));
    float x1 = b2f((u16)(pr >> 16));

    float ss = x0 * x0 + x1 * x1;
    #pragma unroll
    for (int off = 32; off; off >>= 1) ss += __shfl_xor(ss, off);
    float r = rsqrtf(ss * (1.0f / 128.0f) + 1e-6f);

    float y0 = x0 * r * nw[2 * t];
    float y1 = x1 * r * nw[2 * t + 1];
    float c0 = cosb[tok * HD + 2 * t];
    float c1 = cosb[tok * HD + 2 * t + 1];
    float s0 = sinb[tok * HD + 2 * t];
    float s1 = sinb[tok * HD + 2 * t + 1];
    float o0 = y0 * c0 - y1 * s0;
    float o1 = y1 * c1 + y0 * s1;
    *reinterpret_cast<u32*>(&buf[base]) = pk2(o0, o1);
}

// ---------------------------------------------------------------------------
// MFMA flash attention, M_rep=2 rework (prior measured round: MfmaUtil=11.3%,
// LDS-pipe-bound — ~176KB LDS traffic vs ~310 MFMA-cycles per block-tile).
//   - M_rep=2: each wave owns 32 q rows (block q-tile 128). kf/vf LDS
//     fragment reads are reused across both row-sets -> LDS bytes per MFMA
//     drop ~1.75x.
//   - T14 async stage: K/V tile t+1 global loads issue before compute of
//     tile t; regs->LDS write happens after the next barrier.
//   - s_setprio(1) around PV MFMA cluster (T5).
// FIX vs failed round: Ks row stride must be 136 (128 HD elems + 8 pad) —
// the [72]-stride version wrote/read past the row (OOB LDS -> GPU fault).
// LDS: 17408 (Ks) + 18432 (VTs) + 18432 (Ps) = 54272 B -> 2 blocks/CU.
// ---------------------------------------------------------------------------
__global__ __launch_bounds__(256, 2) void attn_kernel(
    const u16* __restrict__ Qf, const u16* __restrict__ Kf,
    const u16* __restrict__ VTg, u16* __restrict__ AO)
{
    __shared__ u16 Ks[64][136];
    __shared__ u16 VTs[128][72];
    __shared__ u16 Ps[4][32][72];

    const int t    = threadIdx.x;
    const int w    = t >> 6;
    const int lane = t & 63;
    const int col  = lane & 15;
    const int quad = lane >> 4;
    const int h    = blockIdx.y;
    const int q0   = blockIdx.x * 128;
    const bool is_ref = (q0 >= TXT) && (q0 < TXT + 512);
    const int ks = is_ref ? TXT : 0;
    const int ke = is_ref ? (TXT + 512) : STOT;

    // Q fragments: two row-sets of 16; wave covers q rows [q0+w*32, q0+w*32+32)
    bf16x8 Qfrag[2][4];
    #pragma unroll
    for (int s = 0; s < 2; s++) {
        const size_t qbase = (size_t)(q0 + w * 32 + s * 16 + col) * DIM + h * HD;
        #pragma unroll
        for (int c = 0; c < 4; c++)
            Qfrag[s][c] = *reinterpret_cast<const bf16x8*>(&Qf[qbase + c * 32 + quad * 8]);
    }

    f32x4 O[2][8];
    f32x4 m[2], l[2];
    #pragma unroll
    for (int s = 0; s < 2; s++) {
        #pragma unroll
        for (int dt = 0; dt < 8; dt++) O[s][dt] = (f32x4){0.f, 0.f, 0.f, 0.f};
        m[s] = (f32x4){-1e30f, -1e30f, -1e30f, -1e30f};
        l[s] = (f32x4){0.f, 0.f, 0.f, 0.f};
    }

    const int krow = t >> 2, kseg = t & 3;
    const int vrow = t >> 1, vseg = t & 1;

    // prologue: load first K/V tile into registers
    u32x4 kreg[4], vreg[4];
    {
        const u32x4* src = reinterpret_cast<const u32x4*>(
            &Kf[(size_t)(ks + krow) * DIM + h * HD + kseg * 32]);
        kreg[0] = src[0]; kreg[1] = src[1]; kreg[2] = src[2]; kreg[3] = src[3];
        const u32x4* vsrc = reinterpret_cast<const u32x4*>(
            &VTg[(size_t)(h * HD + vrow) * STOT + ks + vseg * 32]);
        vreg[0] = vsrc[0]; vreg[1] = vsrc[1]; vreg[2] = vsrc[2]; vreg[3] = vsrc[3];
    }

    for (int k0 = ks; k0 < ke; k0 += 64) {
        __syncthreads();   // prior tile's LDS reads complete
        {
            u32x4* dst = reinterpret_cast<u32x4*>(&Ks[krow][kseg * 32]);
            dst[0] = kreg[0]; dst[1] = kreg[1]; dst[2] = kreg[2]; dst[3] = kreg[3];
            u32x4* vdst = reinterpret_cast<u32x4*>(&VTs[vrow][vseg * 32]);
            vdst[0] = vreg[0]; vdst[1] = vreg[1]; vdst[2] = vreg[2]; vdst[3] = vreg[3];
        }
        __syncthreads();

        // async prefetch of next tile: issue now, consumed at next loop top
        if (k0 + 64 < ke) {
            const u32x4* src = reinterpret_cast<const u32x4*>(
                &Kf[(size_t)(k0 + 64 + krow) * DIM + h * HD + kseg * 32]);
            kreg[0] = src[0]; kreg[1] = src[1]; kreg[2] = src[2]; kreg[3] = src[3];
            const u32x4* vsrc = reinterpret_cast<const u32x4*>(
                &VTg[(size_t)(h * HD + vrow) * STOT + k0 + 64 + vseg * 32]);
            vreg[0] = vsrc[0]; vreg[1] = vsrc[1]; vreg[2] = vsrc[2]; vreg[3] = vsrc[3];
        }

        // QK^T: kf fragments read once, used by both row-sets
        f32x4 sc[2][4];
        #pragma unroll
        for (int kt = 0; kt < 4; kt++) {
            f32x4 a0 = (f32x4){0.f, 0.f, 0.f, 0.f};
            f32x4 a1 = (f32x4){0.f, 0.f, 0.f, 0.f};
            #pragma unroll
            for (int c = 0; c < 4; c++) {
                bf16x8 kf = *reinterpret_cast<const bf16x8*>(
                    &Ks[kt * 16 + col][c * 32 + quad * 8]);
                a0 = __builtin_amdgcn_mfma_f32_16x16x32_bf16(Qfrag[0][c], kf, a0, 0, 0, 0);
                a1 = __builtin_amdgcn_mfma_f32_16x16x32_bf16(Qfrag[1][c], kf, a1, 0, 0, 0);
            }
            sc[0][kt] = a0 * SOFTMAX_SCALE;
            sc[1][kt] = a1 * SOFTMAX_SCALE;
        }

        // online softmax per row-set
        f32x4 alpha[2];
        #pragma unroll
        for (int s = 0; s < 2; s++) {
            f32x4 tmax = max4(max4(sc[s][0], sc[s][1]), max4(sc[s][2], sc[s][3]));
            tmax = max4(tmax, shfl_xor4(tmax, 1));
            tmax = max4(tmax, shfl_xor4(tmax, 2));
            tmax = max4(tmax, shfl_xor4(tmax, 4));
            tmax = max4(tmax, shfl_xor4(tmax, 8));
            f32x4 mnew = max4(m[s], tmax);
            f32x4 rowsum = (f32x4){0.f, 0.f, 0.f, 0.f};
            #pragma unroll
            for (int r = 0; r < 4; r++) alpha[s][r] = __expf(m[s][r] - mnew[r]);
            f32x4 p[4];
            #pragma unroll
            for (int kt = 0; kt < 4; kt++)
                #pragma unroll
                for (int r = 0; r < 4; r++) {
                    p[kt][r] = __expf(sc[s][kt][r] - mnew[r]);
                    rowsum[r] += p[kt][r];
                }
            rowsum += shfl_xor4(rowsum, 1);
            rowsum += shfl_xor4(rowsum, 2);
            rowsum += shfl_xor4(rowsum, 4);
            rowsum += shfl_xor4(rowsum, 8);
            #pragma unroll
            for (int r = 0; r < 4; r++) l[s][r] = l[s][r] * alpha[s][r] + rowsum[r];
            m[s] = mnew;
            #pragma unroll
            for (int dt = 0; dt < 8; dt++)
                #pragma unroll
                for (int r = 0; r < 4; r++) O[s][dt][r] *= alpha[s][r];
            #pragma unroll
            for (int kt = 0; kt < 4; kt++)
                #pragma unroll
                for (int r = 0; r < 4; r++)
                    Ps[w][s * 16 + quad * 4 + r][kt * 16 + col] = f2b(p[kt][r]);
        }

        // PV: vf fragments read once, used by both row-sets
        __builtin_amdgcn_s_setprio(1);
        #pragma unroll
        for (int c = 0; c < 2; c++) {
            bf16x8 pf0 = *reinterpret_cast<const bf16x8*>(
                &Ps[w][col][c * 32 + quad * 8]);
            bf16x8 pf1 = *reinterpret_cast<const bf16x8*>(
                &Ps[w][16 + col][c * 32 + quad * 8]);
            #pragma unroll
            for (int dt = 0; dt < 8; dt++) {
                bf16x8 vf = *reinterpret_cast<const bf16x8*>(
                    &VTs[dt * 16 + col][c * 32 + quad * 8]);
                O[0][dt] = __builtin_amdgcn_mfma_f32_16x16x32_bf16(pf0, vf, O[0][dt], 0, 0, 0);
                O[1][dt] = __builtin_amdgcn_mfma_f32_16x16x32_bf16(pf1, vf, O[1][dt], 0, 0, 0);
            }
        }
        __builtin_amdgcn_s_setprio(0);
    }

    #pragma unroll
    for (int s = 0; s < 2; s++) {
        f32x4 inv;
        #pragma unroll
        for (int r = 0; r < 4; r++) inv[r] = 1.0f / l[s][r];
        #pragma unroll
        for (int dt = 0; dt < 8; dt++)
            #pragma unroll
            for (int r = 0; r < 4; r++)
                AO[(size_t)(q0 + w * 32 + s * 16 + quad * 4 + r) * DIM + h * HD + dt * 16 + col] =
                    f2b(O[s][dt][r] * inv[r]);
    }
}

// ---------------------------------------------------------------------------
// Buffer plan:
//   Qf/AO = d_ws            [STOT*DIM bf16] 15.7 MB
//   WT    = d_ws + 15.7 MB  [up to DIM*DIM bf16] (tiered on ws_size)
//   Kf    = d_out lower     [STOT*DIM bf16]
//   VTg   = d_out upper     [DIM][STOT] bf16
// ---------------------------------------------------------------------------
extern "C" void kernel_launch(void* const* d_in, const int* in_sizes, int n_in,
                              void* d_out, int out_size, void* d_ws, size_t ws_size,
                              hipStream_t stream)
{
    const void*  hs  = d_in[0];
    const void*  enc = d_in[1];
    const float* rc  = (const float*)d_in[2];
    const float* rs  = (const float*)d_in[3];
    const float* wq  = (const float*)d_in[4];  const float* bq  = (const float*)d_in[5];
    const float* wk  = (const float*)d_in[6];  const float* bk  = (const float*)d_in[7];
    const float* wv  = (const float*)d_in[8];  const float* bv  = (const float*)d_in[9];
    const float* waq = (const float*)d_in[10]; const float* baq = (const float*)d_in[11];
    const float* wak = (const float*)d_in[12]; const float* bak = (const float*)d_in[13];
    const float* wav = (const float*)d_in[14]; const float* bav = (const float*)d_in[15];
    const float* nq  = (const float*)d_in[16]; const float* nk  = (const float*)d_in[17];
    const float* naq = (const float*)d_in[18]; const float* nak = (const float*)d_in[19];
    const float* wo  = (const float*)d_in[20]; const float* bo  = (const float*)d_in[21];
    const float* wao = (const float*)d_in[22]; const float* bao = (const float*)d_in[23];

    const size_t QFB = (size_t)STOT * DIM * sizeof(u16);      // 15,728,640
    const size_t WTF = (size_t)DIM * DIM * sizeof(u16);       // 18,874,368
    u16* Qf  = (u16*)d_ws;
    u16* WT  = (u16*)((char*)d_ws + QFB);
    u16* Kf  = (u16*)d_out;
    u16* VTg = (u16*)d_out + (size_t)STOT * DIM;
    u16* AO  = Qf;

    dim3 blk(256);

    int nchunk;
    if      (ws_size >= QFB + WTF)     nchunk = DIM;
    else if (ws_size >= QFB + WTF / 2) nchunk = DIM / 2;
    else                               nchunk = 0;

    if (nchunk > 0) {
        dim3 tgrid(DIM / 64, nchunk / 64);
        #define RUN_GEMM(AF32_, MODE_, MT_, Aptr, Wptr, Bias, Cptr, Coff, M_)     \
            for (int nb = 0; nb < DIM; nb += nchunk) {                            \
                transpose_w_kernel<<<tgrid, blk, 0, stream>>>(Wptr, WT, DIM, DIM, nb); \
                gemm_bt_kernel<AF32_, MODE_, MT_><<<dim3((M_) / MT_, nchunk / 128), blk, 0, stream>>>( \
                    Aptr, WT, Bias, Cptr, Coff, M_, DIM, DIM, nb);                \
            }
        RUN_GEMM(1, 0, 128, hs,  wq,  bq,  Qf,  (size_t)TXT * DIM, SEQ)
        RUN_GEMM(1, 0, 128, hs,  wk,  bk,  Kf,  (size_t)TXT * DIM, SEQ)
        RUN_GEMM(1, 2, 128, hs,  wv,  bv,  VTg, (size_t)TXT,       SEQ)
        RUN_GEMM(1, 0, 64,  enc, waq, baq, Qf,  0,                 TXT)
        RUN_GEMM(1, 0, 64,  enc, wak, bak, Kf,  0,                 TXT)
        RUN_GEMM(1, 2, 64,  enc, wav, bav, VTg, 0,                 TXT)
        rmsrope_kernel<<<dim3(NH, STOT / 4, 2), blk, 0, stream>>>(Qf, Kf, nq, nk, naq, nak, rc, rs);
        attn_kernel<<<dim3(STOT / 128, NH), blk, 0, stream>>>(Qf, Kf, VTg, AO);
        RUN_GEMM(0, 1, 128, AO + (size_t)TXT * DIM, wo,  bo,  d_out, 0,                 SEQ)
        RUN_GEMM(0, 1, 64,  AO,                     wao, bao, d_out, (size_t)SEQ * DIM, TXT)
        #undef RUN_GEMM
    } else {
        gemm_bias_kernel<1,0><<<dim3(SEQ / 128, DIM / 128), blk, 0, stream>>>(hs, wq, bq, Qf, (size_t)TXT * DIM, SEQ, DIM, DIM);
        gemm_bias_kernel<1,0><<<dim3(SEQ / 128, DIM / 128), blk, 0, stream>>>(hs, wk, bk, Kf, (size_t)TXT * DIM, SEQ, DIM, DIM);
        gemm_bias_kernel<1,2><<<dim3(SEQ / 128, DIM / 128), blk, 0, stream>>>(hs, wv, bv, VTg, (size_t)TXT, SEQ, DIM, DIM);
        gemm_bias_kernel<1,0><<<dim3(TXT / 128, DIM / 128), blk, 0, stream>>>(enc, waq, baq, Qf, 0, TXT, DIM, DIM);
        gemm_bias_kernel<1,0><<<dim3(TXT / 128, DIM / 128), blk, 0, stream>>>(enc, wak, bak, Kf, 0, TXT, DIM, DIM);
        gemm_bias_kernel<1,2><<<dim3(TXT / 128, DIM / 128), blk, 0, stream>>>(enc, wav, bav, VTg, 0, TXT, DIM, DIM);
        rmsrope_kernel<<<dim3(NH, STOT / 4, 2), blk, 0, stream>>>(Qf, Kf, nq, nk, naq, nak, rc, rs);
        attn_kernel<<<dim3(STOT / 128, NH), blk, 0, stream>>>(Qf, Kf, VTg, AO);
        gemm_bias_kernel<0,1><<<dim3(SEQ / 128, DIM / 128), blk, 0, stream>>>(AO + (size_t)TXT * DIM, wo, bo, d_out, 0, SEQ, DIM, DIM);
        gemm_bias_kernel<0,1><<<dim3(TXT / 128, DIM / 128), blk, 0, stream>>>(AO, wao, bao, d_out, (size_t)SEQ * DIM, TXT, DIM, DIM);
    }
}

// Round 3
// 1035.464 us; speedup vs baseline: 1.2601x; 1.2001x over previous
//
#include <hip/hip_runtime.h>
#include <hip/hip_bf16.h>

typedef unsigned short u16;
typedef unsigned int u32;
typedef __bf16 bf16x8 __attribute__((ext_vector_type(8)));
typedef float f32x4 __attribute__((ext_vector_type(4)));
typedef unsigned int u32x4 __attribute__((ext_vector_type(4)));
typedef unsigned int u32x2 __attribute__((ext_vector_type(2)));

#define TXT 512
#define SEQ 2048
#define STOT 2560
#define DIM 3072
#define NH 24
#define HD 128
#define SOFTMAX_SCALE 0.08838834764831845f

typedef const __attribute__((address_space(1))) void gas_void;
typedef __attribute__((address_space(3))) void las_void;

__device__ __forceinline__ float b2f(u16 u) {
    union { u32 i; float f; } c; c.i = ((u32)u) << 16; return c.f;
}
__device__ __forceinline__ u16 f2b(float f) {
    union { float f; u32 i; } c; c.f = f;
    u32 x = c.i;
    return (u16)((x + 0x7FFFu + ((x >> 16) & 1u)) >> 16);
}
__device__ __forceinline__ u32 pk2(float a, float b) {
    __hip_bfloat162 h = __float22bfloat162_rn(make_float2(a, b));
    return *reinterpret_cast<u32*>(&h);
}
__device__ __forceinline__ f32x4 max4(f32x4 a, f32x4 b) {
    return (f32x4){fmaxf(a[0], b[0]), fmaxf(a[1], b[1]),
                   fmaxf(a[2], b[2]), fmaxf(a[3], b[3])};
}
__device__ __forceinline__ f32x4 shfl_xor4(f32x4 v, int mask) {
    return (f32x4){__shfl_xor(v[0], mask), __shfl_xor(v[1], mask),
                   __shfl_xor(v[2], mask), __shfl_xor(v[3], mask)};
}

// ---------------------------------------------------------------------------
// convert_bf16: fp32 -> bf16, 8 elems/thread.
// ---------------------------------------------------------------------------
__global__ __launch_bounds__(256) void convert_bf16_kernel(
    const float* __restrict__ src, u16* __restrict__ dst, int n8)
{
    int i = blockIdx.x * 256 + threadIdx.x;
    if (i < n8) {
        const f32x4* p = reinterpret_cast<const f32x4*>(src + (size_t)i * 8);
        f32x4 a = p[0], b = p[1];
        u32x4 o = {pk2(a[0], a[1]), pk2(a[2], a[3]), pk2(b[0], b[1]), pk2(b[2], b[3])};
        *reinterpret_cast<u32x4*>(dst + (size_t)i * 8) = o;
    }
}

// ---------------------------------------------------------------------------
// transpose_w: W fp32 [K][Ntot] -> WT bf16 [ncols][K] (ncols from nbase).
// ---------------------------------------------------------------------------
__global__ __launch_bounds__(256, 2) void transpose_w_kernel(
    const float* __restrict__ W, u16* __restrict__ WT,
    int K, int Ntot, int nbase)
{
    __shared__ u16 Ts[64][66];
    const int t   = threadIdx.x;
    const int k0  = blockIdx.x * 64;
    const int n0l = blockIdx.y * 64;
    const int n0g = nbase + n0l;

    {
        const int krow = t >> 2;
        const int nseg = (t & 3) * 16;
        const float* src = &W[(size_t)(k0 + krow) * Ntot + n0g + nseg];
        f32x4 v0 = reinterpret_cast<const f32x4*>(src)[0];
        f32x4 v1 = reinterpret_cast<const f32x4*>(src)[1];
        f32x4 v2 = reinterpret_cast<const f32x4*>(src)[2];
        f32x4 v3 = reinterpret_cast<const f32x4*>(src)[3];
        #pragma unroll
        for (int i = 0; i < 4; i++) Ts[nseg +      i][krow] = f2b(v0[i]);
        #pragma unroll
        for (int i = 0; i < 4; i++) Ts[nseg +  4 + i][krow] = f2b(v1[i]);
        #pragma unroll
        for (int i = 0; i < 4; i++) Ts[nseg +  8 + i][krow] = f2b(v2[i]);
        #pragma unroll
        for (int i = 0; i < 4; i++) Ts[nseg + 12 + i][krow] = f2b(v3[i]);
    }
    __syncthreads();
    {
        const int nrow = t >> 2;
        const int kseg = (t & 3) * 16;
        u32 out[8];
        #pragma unroll
        for (int c = 0; c < 8; c++)
            out[c] = (u32)Ts[nrow][kseg + 2 * c] | ((u32)Ts[nrow][kseg + 2 * c + 1] << 16);
        u16* dst = &WT[(size_t)(n0l + nrow) * K + k0 + kseg];
        *reinterpret_cast<u32x4*>(dst)     = (u32x4){out[0], out[1], out[2], out[3]};
        *reinterpret_cast<u32x4*>(dst + 8) = (u32x4){out[4], out[5], out[6], out[7]};
    }
}

// ---------------------------------------------------------------------------
// gemm_bt2: C = A[M,K]@B + bias. A bf16 [m][k], BT bf16 [n][k]. Both operands
// staged via global_load_lds width=16 into LINEAR LDS (m97 structure,
// 874-TF class vs ~650 for reg-staging). 2-barrier K-loop, BK=64.
// OUTMODE: 0 bf16 row-major, 1 fp32 row-major, 2 bf16 transposed VT[N][STOT].
// ---------------------------------------------------------------------------
template<int OUTMODE, int MT>
__global__ __launch_bounds__(256, 2) void gemm_bt2_kernel(
    const u16* __restrict__ A, const u16* __restrict__ BT,
    const float* __restrict__ bias, void* __restrict__ Cv, size_t coff,
    int K, int Ntot, int ncol0)
{
    constexpr int MI  = MT / 32;   // acc row-tiles per wave
    constexpr int ASP = MT / 32;   // A 4KB staging spans
    __shared__ __align__(16) u16 As[MT][64];
    __shared__ __align__(16) u16 Bs[128][64];

    const int t    = threadIdx.x;
    const int lane = t & 63;
    const int wave = t >> 6;
    const int wr   = wave >> 1;
    const int wc   = wave & 1;
    const int m0   = blockIdx.x * MT;
    const int n0   = blockIdx.y * 128;
    const int fm   = lane & 15;
    const int fq   = lane >> 4;

    // staging: thread t owns the 16B chunk at flat LDS byte t*16 within each
    // 4KB span; global row = s*32 + t/8, k-chunk = (t&7)*8 elems.
    const int srow = t >> 3;
    const int skb  = (t & 7) * 8;

    f32x4 acc[MI][4];
    #pragma unroll
    for (int i = 0; i < MI; i++)
        #pragma unroll
        for (int j = 0; j < 4; j++)
            acc[i][j] = (f32x4){0.f, 0.f, 0.f, 0.f};

    const u16* aBase = A  + (size_t)(m0 + srow) * K + skb;
    const u16* bBase = BT + (size_t)(n0 + srow) * K + skb;
    char* asDst = (char*)&As[0][0] + (size_t)wave * 1024;   // wave-uniform
    char* bsDst = (char*)&Bs[0][0] + (size_t)wave * 1024;

    for (int k0 = 0; k0 < K; k0 += 64) {
        __syncthreads();   // prior iteration's LDS reads complete
        #pragma unroll
        for (int s = 0; s < 4; s++)
            __builtin_amdgcn_global_load_lds(
                (gas_void*)(bBase + (size_t)(s * 32) * K + k0),
                (las_void*)(bsDst + s * 4096), 16, 0, 0);
        #pragma unroll
        for (int s = 0; s < ASP; s++)
            __builtin_amdgcn_global_load_lds(
                (gas_void*)(aBase + (size_t)(s * 32) * K + k0),
                (las_void*)(asDst + s * 4096), 16, 0, 0);
        __syncthreads();   // compiler drains vmcnt(0) before this barrier

        #pragma unroll
        for (int h = 0; h < 2; h++) {
            bf16x8 af[MI], bfr[4];
            #pragma unroll
            for (int i = 0; i < MI; i++)
                af[i] = *reinterpret_cast<const bf16x8*>(
                    &As[wr * (MT / 2) + i * 16 + fm][h * 32 + fq * 8]);
            #pragma unroll
            for (int j = 0; j < 4; j++)
                bfr[j] = *reinterpret_cast<const bf16x8*>(
                    &Bs[wc * 64 + j * 16 + fm][h * 32 + fq * 8]);
            #pragma unroll
            for (int i = 0; i < MI; i++)
                #pragma unroll
                for (int j = 0; j < 4; j++)
                    acc[i][j] = __builtin_amdgcn_mfma_f32_16x16x32_bf16(af[i], bfr[j], acc[i][j], 0, 0, 0);
        }
    }

    // epilogue: C/D layout col = lane&15, row = (lane>>4)*4 + r
    #pragma unroll
    for (int i = 0; i < MI; i++) {
        #pragma unroll
        for (int j = 0; j < 4; j++) {
            int col = ncol0 + n0 + wc * 64 + j * 16 + fm;
            float bb = bias[col];
            if (OUTMODE == 2) {
                int tok = (int)coff + m0 + wr * (MT / 2) + i * 16 + fq * 4;
                u32x2 pr = {pk2(acc[i][j][0] + bb, acc[i][j][1] + bb),
                            pk2(acc[i][j][2] + bb, acc[i][j][3] + bb)};
                *reinterpret_cast<u32x2*>(&((u16*)Cv)[(size_t)col * STOT + tok]) = pr;
            } else {
                #pragma unroll
                for (int r = 0; r < 4; r++) {
                    int row = m0 + wr * (MT / 2) + i * 16 + fq * 4 + r;
                    size_t idx = coff + (size_t)row * Ntot + col;
                    float val = acc[i][j][r] + bb;
                    if (OUTMODE == 1) ((float*)Cv)[idx] = val;
                    else              ((u16*)Cv)[idx]   = f2b(val);
                }
            }
        }
    }
}

// ---------------------------------------------------------------------------
// gemm_bt: verified R2 path (reg-staged, padded LDS). Kept for the fallback
// tier when ws is too small for the bf16-A buffer.
// ---------------------------------------------------------------------------
template<int AF32, int OUTMODE, int MT>
__global__ __launch_bounds__(256, 2) void gemm_bt_kernel(
    const void* __restrict__ Av, const u16* __restrict__ BT,
    const float* __restrict__ bias, void* __restrict__ Cv, size_t coff,
    int M, int K, int Ntot, int ncol0)
{
    constexpr int MI = MT / 32;
    constexpr int ASEGN = (MT == 128) ? 32 : 16;
    __shared__ u16 As[MT][72];
    __shared__ u16 Bs[128][72];

    const int t    = threadIdx.x;
    const int lane = t & 63;
    const int wave = t >> 6;
    const int wr   = wave >> 1;
    const int wc   = wave & 1;
    const int m0   = blockIdx.x * MT;
    const int n0   = blockIdx.y * 128;
    const int fm   = lane & 15;
    const int fq   = lane >> 4;

    const int arow = (MT == 128) ? (t >> 1) : (t >> 2);
    const int aseg = (MT == 128) ? ((t & 1) * 32) : ((t & 3) * 16);
    const int brow = t >> 1;
    const int bseg = (t & 1) * 32;

    f32x4 acc[MI][4];
    #pragma unroll
    for (int i = 0; i < MI; i++)
        #pragma unroll
        for (int j = 0; j < 4; j++)
            acc[i][j] = (f32x4){0.f, 0.f, 0.f, 0.f};

    for (int k0 = 0; k0 < K; k0 += 64) {
        u32 aw[ASEGN / 2];
        if (AF32) {
            const float* ap = (const float*)Av + (size_t)(m0 + arow) * K + k0 + aseg;
            #pragma unroll
            for (int c = 0; c < ASEGN / 4; c++) {
                f32x4 x = reinterpret_cast<const f32x4*>(ap)[c];
                aw[2 * c]     = pk2(x[0], x[1]);
                aw[2 * c + 1] = pk2(x[2], x[3]);
            }
        } else {
            const u32x4* ap = reinterpret_cast<const u32x4*>(
                (const u16*)Av + (size_t)(m0 + arow) * K + k0 + aseg);
            #pragma unroll
            for (int c = 0; c < ASEGN / 8; c++) {
                u32x4 x = ap[c];
                aw[4 * c] = x[0]; aw[4 * c + 1] = x[1];
                aw[4 * c + 2] = x[2]; aw[4 * c + 3] = x[3];
            }
        }
        u32x4 bw[4];
        {
            const u32x4* bp = reinterpret_cast<const u32x4*>(
                &BT[(size_t)(n0 + brow) * K + k0 + bseg]);
            bw[0] = bp[0]; bw[1] = bp[1]; bw[2] = bp[2]; bw[3] = bp[3];
        }
        __syncthreads();
        #pragma unroll
        for (int c = 0; c < ASEGN / 8; c++)
            *reinterpret_cast<u32x4*>(&As[arow][aseg + c * 8]) =
                (u32x4){aw[4 * c], aw[4 * c + 1], aw[4 * c + 2], aw[4 * c + 3]};
        #pragma unroll
        for (int c = 0; c < 4; c++)
            *reinterpret_cast<u32x4*>(&Bs[brow][bseg + c * 8]) = bw[c];
        __syncthreads();

        #pragma unroll
        for (int h = 0; h < 2; h++) {
            bf16x8 af[MI], bfr[4];
            #pragma unroll
            for (int i = 0; i < MI; i++)
                af[i] = *reinterpret_cast<const bf16x8*>(
                    &As[wr * (MT / 2) + i * 16 + fm][h * 32 + fq * 8]);
            #pragma unroll
            for (int j = 0; j < 4; j++)
                bfr[j] = *reinterpret_cast<const bf16x8*>(
                    &Bs[wc * 64 + j * 16 + fm][h * 32 + fq * 8]);
            #pragma unroll
            for (int i = 0; i < MI; i++)
                #pragma unroll
                for (int j = 0; j < 4; j++)
                    acc[i][j] = __builtin_amdgcn_mfma_f32_16x16x32_bf16(af[i], bfr[j], acc[i][j], 0, 0, 0);
        }
    }

    #pragma unroll
    for (int i = 0; i < MI; i++) {
        #pragma unroll
        for (int j = 0; j < 4; j++) {
            int col = ncol0 + n0 + wc * 64 + j * 16 + fm;
            float bb = bias[col];
            if (OUTMODE == 2) {
                int tok = (int)coff + m0 + wr * (MT / 2) + i * 16 + fq * 4;
                u32x2 pr = {pk2(acc[i][j][0] + bb, acc[i][j][1] + bb),
                            pk2(acc[i][j][2] + bb, acc[i][j][3] + bb)};
                *reinterpret_cast<u32x2*>(&((u16*)Cv)[(size_t)col * STOT + tok]) = pr;
            } else {
                #pragma unroll
                for (int r = 0; r < 4; r++) {
                    int row = m0 + wr * (MT / 2) + i * 16 + fq * 4 + r;
                    size_t idx = coff + (size_t)row * Ntot + col;
                    float val = acc[i][j][r] + bb;
                    if (OUTMODE == 1) ((float*)Cv)[idx] = val;
                    else              ((u16*)Cv)[idx]   = f2b(val);
                }
            }
        }
    }
}

// ---------------------------------------------------------------------------
// Fallback GEMM (fp32 W, scalar staging, BK=32) — only if ws too small.
// ---------------------------------------------------------------------------
template<int AF32, int OUTMODE>
__global__ __launch_bounds__(256, 2) void gemm_bias_kernel(
    const void* __restrict__ Av, const float* __restrict__ W,
    const float* __restrict__ bias, void* __restrict__ Cv, size_t coff,
    int M, int K, int N)
{
    __shared__ u16 As[128][40];
    __shared__ u16 Bs[128][40];

    const int t    = threadIdx.x;
    const int lane = t & 63;
    const int wave = t >> 6;
    const int wr   = wave >> 1;
    const int wc   = wave & 1;
    const int m0   = blockIdx.x * 128;
    const int n0   = blockIdx.y * 128;
    const int fm   = lane & 15;
    const int fq   = lane >> 4;

    const int arow = t >> 1;
    const int akg  = (t & 1) * 16;
    const int bn   = t >> 1;
    const int bkg  = (t & 1) * 16;

    f32x4 acc[4][4];
    #pragma unroll
    for (int i = 0; i < 4; i++)
        #pragma unroll
        for (int j = 0; j < 4; j++)
            acc[i][j] = (f32x4){0.f, 0.f, 0.f, 0.f};

    for (int k0 = 0; k0 < K; k0 += 32) {
        u32x4 a0, a1;
        if (AF32) {
            const f32x4* p = reinterpret_cast<const f32x4*>(
                (const float*)Av + (size_t)(m0 + arow) * K + k0 + akg);
            f32x4 x0 = p[0], x1 = p[1], x2 = p[2], x3 = p[3];
            a0 = (u32x4){pk2(x0[0], x0[1]), pk2(x0[2], x0[3]),
                         pk2(x1[0], x1[1]), pk2(x1[2], x1[3])};
            a1 = (u32x4){pk2(x2[0], x2[1]), pk2(x2[2], x2[3]),
                         pk2(x3[0], x3[1]), pk2(x3[2], x3[3])};
        } else {
            const u32x4* p = reinterpret_cast<const u32x4*>(
                (const u16*)Av + (size_t)(m0 + arow) * K + k0 + akg);
            a0 = p[0]; a1 = p[1];
        }
        float wv[16];
        #pragma unroll
        for (int j = 0; j < 16; j++)
            wv[j] = W[(size_t)(k0 + bkg + j) * N + n0 + bn];
        u32x4 b0, b1;
        #pragma unroll
        for (int j = 0; j < 4; j++) {
            b0[j] = pk2(wv[2 * j],     wv[2 * j + 1]);
            b1[j] = pk2(wv[8 + 2 * j], wv[8 + 2 * j + 1]);
        }
        __syncthreads();
        *reinterpret_cast<u32x4*>(&As[arow][akg])     = a0;
        *reinterpret_cast<u32x4*>(&As[arow][akg + 8]) = a1;
        *reinterpret_cast<u32x4*>(&Bs[bn][bkg])       = b0;
        *reinterpret_cast<u32x4*>(&Bs[bn][bkg + 8])   = b1;
        __syncthreads();

        bf16x8 af[4], bfr[4];
        #pragma unroll
        for (int i = 0; i < 4; i++)
            af[i] = *reinterpret_cast<const bf16x8*>(&As[wr * 64 + i * 16 + fm][fq * 8]);
        #pragma unroll
        for (int j = 0; j < 4; j++)
            bfr[j] = *reinterpret_cast<const bf16x8*>(&Bs[wc * 64 + j * 16 + fm][fq * 8]);
        #pragma unroll
        for (int i = 0; i < 4; i++)
            #pragma unroll
            for (int j = 0; j < 4; j++)
                acc[i][j] = __builtin_amdgcn_mfma_f32_16x16x32_bf16(af[i], bfr[j], acc[i][j], 0, 0, 0);
    }

    #pragma unroll
    for (int i = 0; i < 4; i++) {
        #pragma unroll
        for (int j = 0; j < 4; j++) {
            int col = n0 + wc * 64 + j * 16 + fm;
            float bb = bias[col];
            if (OUTMODE == 2) {
                int tok = (int)coff + m0 + wr * 64 + i * 16 + fq * 4;
                u32x2 pr = {pk2(acc[i][j][0] + bb, acc[i][j][1] + bb),
                            pk2(acc[i][j][2] + bb, acc[i][j][3] + bb)};
                *reinterpret_cast<u32x2*>(&((u16*)Cv)[(size_t)col * STOT + tok]) = pr;
            } else {
                #pragma unroll
                for (int r = 0; r < 4; r++) {
                    int row = m0 + wr * 64 + i * 16 + fq * 4 + r;
                    size_t idx = coff + (size_t)row * N + col;
                    float val = acc[i][j][r] + bb;
                    if (OUTMODE == 1) ((float*)Cv)[idx] = val;
                    else              ((u16*)Cv)[idx]   = f2b(val);
                }
            }
        }
    }
}

// ---------------------------------------------------------------------------
// Fused per-head RMSNorm + RoPE, in place. 4 waves/block, one token each.
// ---------------------------------------------------------------------------
__global__ __launch_bounds__(256) void rmsrope_kernel(
    u16* __restrict__ Qf, u16* __restrict__ Kf,
    const float* __restrict__ nq, const float* __restrict__ nk,
    const float* __restrict__ naq, const float* __restrict__ nak,
    const float* __restrict__ cosb, const float* __restrict__ sinb)
{
    const int h     = blockIdx.x;
    const int tok   = blockIdx.y * 4 + (threadIdx.x >> 6);
    const int which = blockIdx.z;
    u16* buf = which ? Kf : Qf;
    const float* nw = (tok < TXT) ? (which ? nak : naq) : (which ? nk : nq);
    const int t = threadIdx.x & 63;
    const size_t base = (size_t)tok * DIM + h * HD + 2 * t;

    u32 pr = *reinterpret_cast<const u32*>(&buf[base]);
    float x0 = b2f((u16)(pr & 0xFFFF));
    float x1 = b2f((u16)(pr >> 16));

    float ss = x0 * x0 + x1 * x1;
    #pragma unroll
    for (int off = 32; off; off >>= 1) ss += __shfl_xor(ss, off);
    float r = rsqrtf(ss * (1.0f / 128.0f) + 1e-6f);

    float y0 = x0 * r * nw[2 * t];
    float y1 = x1 * r * nw[2 * t + 1];
    float c0 = cosb[tok * HD + 2 * t];
    float c1 = cosb[tok * HD + 2 * t + 1];
    float s0 = sinb[tok * HD + 2 * t];
    float s1 = sinb[tok * HD + 2 * t + 1];
    float o0 = y0 * c0 - y1 * s0;
    float o1 = y1 * c1 + y0 * s1;
    *reinterpret_cast<u32*>(&buf[base]) = pk2(o0, o1);
}

// ---------------------------------------------------------------------------
// MFMA flash attention (M_rep=2, verified R2). R3: attn measured
// VALU-bound (VALUBusy 28.7 vs MfmaUtil 15.6) — cut VALU:
//   - Ps conversion via paired v_cvt_pk_bf16_f32 (pk2) instead of 32 scalar
//     f2b (~100 VALU ops/wave/tile saved).
//   - defer-max (T13, THR=8): skip O-rescale + m-update when tile max growth
//     <= 8 (saves 64 fmul + 4 exp on most tiles; wave-uniform branch).
// ---------------------------------------------------------------------------
__global__ __launch_bounds__(256, 2) void attn_kernel(
    const u16* __restrict__ Qf, const u16* __restrict__ Kf,
    const u16* __restrict__ VTg, u16* __restrict__ AO)
{
    __shared__ u16 Ks[64][136];
    __shared__ u16 VTs[128][72];
    __shared__ u16 Ps[4][32][72];

    const int t    = threadIdx.x;
    const int w    = t >> 6;
    const int lane = t & 63;
    const int col  = lane & 15;
    const int quad = lane >> 4;
    const int h    = blockIdx.y;
    const int q0   = blockIdx.x * 128;
    const bool is_ref = (q0 >= TXT) && (q0 < TXT + 512);
    const int ks = is_ref ? TXT : 0;
    const int ke = is_ref ? (TXT + 512) : STOT;

    bf16x8 Qfrag[2][4];
    #pragma unroll
    for (int s = 0; s < 2; s++) {
        const size_t qbase = (size_t)(q0 + w * 32 + s * 16 + col) * DIM + h * HD;
        #pragma unroll
        for (int c = 0; c < 4; c++)
            Qfrag[s][c] = *reinterpret_cast<const bf16x8*>(&Qf[qbase + c * 32 + quad * 8]);
    }

    f32x4 O[2][8];
    f32x4 m[2], l[2];
    #pragma unroll
    for (int s = 0; s < 2; s++) {
        #pragma unroll
        for (int dt = 0; dt < 8; dt++) O[s][dt] = (f32x4){0.f, 0.f, 0.f, 0.f};
        m[s] = (f32x4){-1e30f, -1e30f, -1e30f, -1e30f};
        l[s] = (f32x4){0.f, 0.f, 0.f, 0.f};
    }

    const int krow = t >> 2, kseg = t & 3;
    const int vrow = t >> 1, vseg = t & 1;

    u32x4 kreg[4], vreg[4];
    {
        const u32x4* src = reinterpret_cast<const u32x4*>(
            &Kf[(size_t)(ks + krow) * DIM + h * HD + kseg * 32]);
        kreg[0] = src[0]; kreg[1] = src[1]; kreg[2] = src[2]; kreg[3] = src[3];
        const u32x4* vsrc = reinterpret_cast<const u32x4*>(
            &VTg[(size_t)(h * HD + vrow) * STOT + ks + vseg * 32]);
        vreg[0] = vsrc[0]; vreg[1] = vsrc[1]; vreg[2] = vsrc[2]; vreg[3] = vsrc[3];
    }

    for (int k0 = ks; k0 < ke; k0 += 64) {
        __syncthreads();
        {
            u32x4* dst = reinterpret_cast<u32x4*>(&Ks[krow][kseg * 32]);
            dst[0] = kreg[0]; dst[1] = kreg[1]; dst[2] = kreg[2]; dst[3] = kreg[3];
            u32x4* vdst = reinterpret_cast<u32x4*>(&VTs[vrow][vseg * 32]);
            vdst[0] = vreg[0]; vdst[1] = vreg[1]; vdst[2] = vreg[2]; vdst[3] = vreg[3];
        }
        __syncthreads();

        if (k0 + 64 < ke) {
            const u32x4* src = reinterpret_cast<const u32x4*>(
                &Kf[(size_t)(k0 + 64 + krow) * DIM + h * HD + kseg * 32]);
            kreg[0] = src[0]; kreg[1] = src[1]; kreg[2] = src[2]; kreg[3] = src[3];
            const u32x4* vsrc = reinterpret_cast<const u32x4*>(
                &VTg[(size_t)(h * HD + vrow) * STOT + k0 + 64 + vseg * 32]);
            vreg[0] = vsrc[0]; vreg[1] = vsrc[1]; vreg[2] = vsrc[2]; vreg[3] = vsrc[3];
        }

        f32x4 sc[2][4];
        #pragma unroll
        for (int kt = 0; kt < 4; kt++) {
            f32x4 a0 = (f32x4){0.f, 0.f, 0.f, 0.f};
            f32x4 a1 = (f32x4){0.f, 0.f, 0.f, 0.f};
            #pragma unroll
            for (int c = 0; c < 4; c++) {
                bf16x8 kf = *reinterpret_cast<const bf16x8*>(
                    &Ks[kt * 16 + col][c * 32 + quad * 8]);
                a0 = __builtin_amdgcn_mfma_f32_16x16x32_bf16(Qfrag[0][c], kf, a0, 0, 0, 0);
                a1 = __builtin_amdgcn_mfma_f32_16x16x32_bf16(Qfrag[1][c], kf, a1, 0, 0, 0);
            }
            sc[0][kt] = a0 * SOFTMAX_SCALE;
            sc[1][kt] = a1 * SOFTMAX_SCALE;
        }

        #pragma unroll
        for (int s = 0; s < 2; s++) {
            f32x4 tmax = max4(max4(sc[s][0], sc[s][1]), max4(sc[s][2], sc[s][3]));
            tmax = max4(tmax, shfl_xor4(tmax, 1));
            tmax = max4(tmax, shfl_xor4(tmax, 2));
            tmax = max4(tmax, shfl_xor4(tmax, 4));
            tmax = max4(tmax, shfl_xor4(tmax, 8));
            const bool ok = (tmax[0] - m[s][0] <= 8.0f) && (tmax[1] - m[s][1] <= 8.0f) &&
                            (tmax[2] - m[s][2] <= 8.0f) && (tmax[3] - m[s][3] <= 8.0f);
            const bool skip = __all(ok);
            f32x4 mnew = skip ? m[s] : max4(m[s], tmax);

            f32x4 rowsum = (f32x4){0.f, 0.f, 0.f, 0.f};
            f32x4 p[4];
            #pragma unroll
            for (int kt = 0; kt < 4; kt++)
                #pragma unroll
                for (int r = 0; r < 4; r++) {
                    p[kt][r] = __expf(sc[s][kt][r] - mnew[r]);
                    rowsum[r] += p[kt][r];
                }
            rowsum += shfl_xor4(rowsum, 1);
            rowsum += shfl_xor4(rowsum, 2);
            rowsum += shfl_xor4(rowsum, 4);
            rowsum += shfl_xor4(rowsum, 8);

            if (skip) {
                #pragma unroll
                for (int r = 0; r < 4; r++) l[s][r] += rowsum[r];
            } else {
                f32x4 alpha;
                #pragma unroll
                for (int r = 0; r < 4; r++) alpha[r] = __expf(m[s][r] - mnew[r]);
                #pragma unroll
                for (int r = 0; r < 4; r++) l[s][r] = l[s][r] * alpha[r] + rowsum[r];
                m[s] = mnew;
                #pragma unroll
                for (int dt = 0; dt < 8; dt++)
                    #pragma unroll
                    for (int r = 0; r < 4; r++) O[s][dt][r] *= alpha[r];
            }

            // Ps write: paired cvt_pk (RNE, same rounding as f2b)
            #pragma unroll
            for (int r = 0; r < 4; r++) {
                u32 w01 = pk2(p[0][r], p[1][r]);
                u32 w23 = pk2(p[2][r], p[3][r]);
                u16* prow = &Ps[w][s * 16 + quad * 4 + r][0];
                prow[col]      = (u16)(w01 & 0xFFFFu);
                prow[col + 16] = (u16)(w01 >> 16);
                prow[col + 32] = (u16)(w23 & 0xFFFFu);
                prow[col + 48] = (u16)(w23 >> 16);
            }
        }

        __builtin_amdgcn_s_setprio(1);
        #pragma unroll
        for (int c = 0; c < 2; c++) {
            bf16x8 pf0 = *reinterpret_cast<const bf16x8*>(
                &Ps[w][col][c * 32 + quad * 8]);
            bf16x8 pf1 = *reinterpret_cast<const bf16x8*>(
                &Ps[w][16 + col][c * 32 + quad * 8]);
            #pragma unroll
            for (int dt = 0; dt < 8; dt++) {
                bf16x8 vf = *reinterpret_cast<const bf16x8*>(
                    &VTs[dt * 16 + col][c * 32 + quad * 8]);
                O[0][dt] = __builtin_amdgcn_mfma_f32_16x16x32_bf16(pf0, vf, O[0][dt], 0, 0, 0);
                O[1][dt] = __builtin_amdgcn_mfma_f32_16x16x32_bf16(pf1, vf, O[1][dt], 0, 0, 0);
            }
        }
        __builtin_amdgcn_s_setprio(0);
    }

    #pragma unroll
    for (int s = 0; s < 2; s++) {
        f32x4 inv;
        #pragma unroll
        for (int r = 0; r < 4; r++) inv[r] = 1.0f / l[s][r];
        #pragma unroll
        for (int dt = 0; dt < 8; dt++)
            #pragma unroll
            for (int r = 0; r < 4; r++)
                AO[(size_t)(q0 + w * 32 + s * 16 + quad * 4 + r) * DIM + h * HD + dt * 16 + col] =
                    f2b(O[s][dt][r] * inv[r]);
    }
}

// ---------------------------------------------------------------------------
// Buffer plan:
//   Qf/AO = d_ws                  [STOT*DIM bf16] 15.7 MB
//   WT    = d_ws + QFB            [DIM*DIM bf16]  18.9 MB (tiered)
//   Xbf   = d_ws + QFB + WTF      [STOT*DIM bf16] 15.7 MB (new top tier only)
//   Kf    = d_out lower           [STOT*DIM bf16]
//   VTg   = d_out upper           [DIM][STOT] bf16
// ---------------------------------------------------------------------------
extern "C" void kernel_launch(void* const* d_in, const int* in_sizes, int n_in,
                              void* d_out, int out_size, void* d_ws, size_t ws_size,
                              hipStream_t stream)
{
    const void*  hs  = d_in[0];
    const void*  enc = d_in[1];
    const float* rc  = (const float*)d_in[2];
    const float* rs  = (const float*)d_in[3];
    const float* wq  = (const float*)d_in[4];  const float* bq  = (const float*)d_in[5];
    const float* wk  = (const float*)d_in[6];  const float* bk  = (const float*)d_in[7];
    const float* wv  = (const float*)d_in[8];  const float* bv  = (const float*)d_in[9];
    const float* waq = (const float*)d_in[10]; const float* baq = (const float*)d_in[11];
    const float* wak = (const float*)d_in[12]; const float* bak = (const float*)d_in[13];
    const float* wav = (const float*)d_in[14]; const float* bav = (const float*)d_in[15];
    const float* nq  = (const float*)d_in[16]; const float* nk  = (const float*)d_in[17];
    const float* naq = (const float*)d_in[18]; const float* nak = (const float*)d_in[19];
    const float* wo  = (const float*)d_in[20]; const float* bo  = (const float*)d_in[21];
    const float* wao = (const float*)d_in[22]; const float* bao = (const float*)d_in[23];

    const size_t QFB = (size_t)STOT * DIM * sizeof(u16);      // 15,728,640
    const size_t WTF = (size_t)DIM * DIM * sizeof(u16);       // 18,874,368
    u16* Qf  = (u16*)d_ws;
    u16* WT  = (u16*)((char*)d_ws + QFB);
    u16* Xbf = (u16*)((char*)d_ws + QFB + WTF);
    u16* Kf  = (u16*)d_out;
    u16* VTg = (u16*)d_out + (size_t)STOT * DIM;
    u16* AO  = Qf;

    dim3 blk(256);

    if (ws_size >= 2 * QFB + WTF) {
        // ---- fast path: bf16 A + global_load_lds GEMMs ----
        convert_bf16_kernel<<<dim3((SEQ * DIM / 8) / 256), blk, 0, stream>>>(
            (const float*)hs, Xbf + (size_t)TXT * DIM, SEQ * DIM / 8);
        convert_bf16_kernel<<<dim3((TXT * DIM / 8) / 256), blk, 0, stream>>>(
            (const float*)enc, Xbf, TXT * DIM / 8);
        dim3 tgrid(DIM / 64, DIM / 64);
        #define RUN2(MODE_, MT_, Aptr, Wptr, Bias, Cptr, Coff, M_)                   \
            transpose_w_kernel<<<tgrid, blk, 0, stream>>>(Wptr, WT, DIM, DIM, 0);    \
            gemm_bt2_kernel<MODE_, MT_><<<dim3((M_) / MT_, DIM / 128), blk, 0, stream>>>( \
                Aptr, WT, Bias, Cptr, Coff, DIM, DIM, 0);
        RUN2(0, 128, Xbf + (size_t)TXT * DIM, wq,  bq,  Qf,  (size_t)TXT * DIM, SEQ)
        RUN2(0, 128, Xbf + (size_t)TXT * DIM, wk,  bk,  Kf,  (size_t)TXT * DIM, SEQ)
        RUN2(2, 128, Xbf + (size_t)TXT * DIM, wv,  bv,  VTg, (size_t)TXT,       SEQ)
        RUN2(0, 64,  Xbf,                     waq, baq, Qf,  0,                 TXT)
        RUN2(0, 64,  Xbf,                     wak, bak, Kf,  0,                 TXT)
        RUN2(2, 64,  Xbf,                     wav, bav, VTg, 0,                 TXT)
        rmsrope_kernel<<<dim3(NH, STOT / 4, 2), blk, 0, stream>>>(Qf, Kf, nq, nk, naq, nak, rc, rs);
        attn_kernel<<<dim3(STOT / 128, NH), blk, 0, stream>>>(Qf, Kf, VTg, AO);
        RUN2(1, 128, AO + (size_t)TXT * DIM, wo,  bo,  d_out, 0,                 SEQ)
        RUN2(1, 64,  AO,                     wao, bao, d_out, (size_t)SEQ * DIM, TXT)
        #undef RUN2
        return;
    }

    int nchunk;
    if      (ws_size >= QFB + WTF)     nchunk = DIM;
    else if (ws_size >= QFB + WTF / 2) nchunk = DIM / 2;
    else                               nchunk = 0;

    if (nchunk > 0) {
        dim3 tgrid(DIM / 64, nchunk / 64);
        #define RUN_GEMM(AF32_, MODE_, MT_, Aptr, Wptr, Bias, Cptr, Coff, M_)     \
            for (int nb = 0; nb < DIM; nb += nchunk) {                            \
                transpose_w_kernel<<<tgrid, blk, 0, stream>>>(Wptr, WT, DIM, DIM, nb); \
                gemm_bt_kernel<AF32_, MODE_, MT_><<<dim3((M_) / MT_, nchunk / 128), blk, 0, stream>>>( \
                    Aptr, WT, Bias, Cptr, Coff, M_, DIM, DIM, nb);                \
            }
        RUN_GEMM(1, 0, 128, hs,  wq,  bq,  Qf,  (size_t)TXT * DIM, SEQ)
        RUN_GEMM(1, 0, 128, hs,  wk,  bk,  Kf,  (size_t)TXT * DIM, SEQ)
        RUN_GEMM(1, 2, 128, hs,  wv,  bv,  VTg, (size_t)TXT,       SEQ)
        RUN_GEMM(1, 0, 64,  enc, waq, baq, Qf,  0,                 TXT)
        RUN_GEMM(1, 0, 64,  enc, wak, bak, Kf,  0,                 TXT)
        RUN_GEMM(1, 2, 64,  enc, wav, bav, VTg, 0,                 TXT)
        rmsrope_kernel<<<dim3(NH, STOT / 4, 2), blk, 0, stream>>>(Qf, Kf, nq, nk, naq, nak, rc, rs);
        attn_kernel<<<dim3(STOT / 128, NH), blk, 0, stream>>>(Qf, Kf, VTg, AO);
        RUN_GEMM(0, 1, 128, AO + (size_t)TXT * DIM, wo,  bo,  d_out, 0,                 SEQ)
        RUN_GEMM(0, 1, 64,  AO,                     wao, bao, d_out, (size_t)SEQ * DIM, TXT)
        #undef RUN_GEMM
    } else {
        gemm_bias_kernel<1,0><<<dim3(SEQ / 128, DIM / 128), blk, 0, stream>>>(hs, wq, bq, Qf, (size_t)TXT * DIM, SEQ, DIM, DIM);
        gemm_bias_kernel<1,0><<<dim3(SEQ / 128, DIM / 128), blk, 0, stream>>>(hs, wk, bk, Kf, (size_t)TXT * DIM, SEQ, DIM, DIM);
        gemm_bias_kernel<1,2><<<dim3(SEQ / 128, DIM / 128), blk, 0, stream>>>(hs, wv, bv, VTg, (size_t)TXT, SEQ, DIM, DIM);
        gemm_bias_kernel<1,0><<<dim3(TXT / 128, DIM / 128), blk, 0, stream>>>(enc, waq, baq, Qf, 0, TXT, DIM, DIM);
        gemm_bias_kernel<1,0><<<dim3(TXT / 128, DIM / 128), blk, 0, stream>>>(enc, wak, bak, Kf, 0, TXT, DIM, DIM);
        gemm_bias_kernel<1,2><<<dim3(TXT / 128, DIM / 128), blk, 0, stream>>>(enc, wav, bav, VTg, 0, TXT, DIM, DIM);
        rmsrope_kernel<<<dim3(NH, STOT / 4, 2), blk, 0, stream>>>(Qf, Kf, nq, nk, naq, nak, rc, rs);
        attn_kernel<<<dim3(STOT / 128, NH), blk, 0, stream>>>(Qf, Kf, VTg, AO);
        gemm_bias_kernel<0,1><<<dim3(SEQ / 128, DIM / 128), blk, 0, stream>>>(AO + (size_t)TXT * DIM, wo, bo, d_out, 0, SEQ, DIM, DIM);
        gemm_bias_kernel<0,1><<<dim3(TXT / 128, DIM / 128), blk, 0, stream>>>(AO, wao, bao, d_out, (size_t)SEQ * DIM, TXT, DIM, DIM);
    }
}

// Round 6
// 1033.217 us; speedup vs baseline: 1.2629x; 1.0022x over previous
//
#include <hip/hip_runtime.h>
#include <hip/hip_bf16.h>

typedef unsigned short u16;
typedef unsigned int u32;
typedef __bf16 bf16x8 __attribute__((ext_vector_type(8)));
typedef float f32x4 __attribute__((ext_vector_type(4)));
typedef unsigned int u32x4 __attribute__((ext_vector_type(4)));
typedef unsigned int u32x2 __attribute__((ext_vector_type(2)));

#define TXT 512
#define SEQ 2048
#define STOT 2560
#define DIM 3072
#define NH 24
#define HD 128
#define SOFTMAX_SCALE 0.08838834764831845f

typedef const __attribute__((address_space(1))) void gas_void;
typedef __attribute__((address_space(3))) void las_void;

__device__ __forceinline__ float b2f(u16 u) {
    union { u32 i; float f; } c; c.i = ((u32)u) << 16; return c.f;
}
__device__ __forceinline__ u16 f2b(float f) {
    union { float f; u32 i; } c; c.f = f;
    u32 x = c.i;
    return (u16)((x + 0x7FFFu + ((x >> 16) & 1u)) >> 16);
}
__device__ __forceinline__ u32 pk2(float a, float b) {
    __hip_bfloat162 h = __float22bfloat162_rn(make_float2(a, b));
    return *reinterpret_cast<u32*>(&h);
}
__device__ __forceinline__ f32x4 max4(f32x4 a, f32x4 b) {
    return (f32x4){fmaxf(a[0], b[0]), fmaxf(a[1], b[1]),
                   fmaxf(a[2], b[2]), fmaxf(a[3], b[3])};
}
__device__ __forceinline__ f32x4 shfl_xor4(f32x4 v, int mask) {
    return (f32x4){__shfl_xor(v[0], mask), __shfl_xor(v[1], mask),
                   __shfl_xor(v[2], mask), __shfl_xor(v[3], mask)};
}

// ---------------------------------------------------------------------------
// convert_bf16: fp32 -> bf16, 8 elems/thread.
// ---------------------------------------------------------------------------
__global__ __launch_bounds__(256) void convert_bf16_kernel(
    const float* __restrict__ src, u16* __restrict__ dst, int n8)
{
    int i = blockIdx.x * 256 + threadIdx.x;
    if (i < n8) {
        const f32x4* p = reinterpret_cast<const f32x4*>(src + (size_t)i * 8);
        f32x4 a = p[0], b = p[1];
        u32x4 o = {pk2(a[0], a[1]), pk2(a[2], a[3]), pk2(b[0], b[1]), pk2(b[2], b[3])};
        *reinterpret_cast<u32x4*>(dst + (size_t)i * 8) = o;
    }
}

// ---------------------------------------------------------------------------
// transpose_w: W fp32 [K][Ntot] -> WT bf16 [ncols][K] (ncols from nbase).
// ---------------------------------------------------------------------------
__global__ __launch_bounds__(256, 2) void transpose_w_kernel(
    const float* __restrict__ W, u16* __restrict__ WT,
    int K, int Ntot, int nbase)
{
    __shared__ u16 Ts[64][66];
    const int t   = threadIdx.x;
    const int k0  = blockIdx.x * 64;
    const int n0l = blockIdx.y * 64;
    const int n0g = nbase + n0l;

    {
        const int krow = t >> 2;
        const int nseg = (t & 3) * 16;
        const float* src = &W[(size_t)(k0 + krow) * Ntot + n0g + nseg];
        f32x4 v0 = reinterpret_cast<const f32x4*>(src)[0];
        f32x4 v1 = reinterpret_cast<const f32x4*>(src)[1];
        f32x4 v2 = reinterpret_cast<const f32x4*>(src)[2];
        f32x4 v3 = reinterpret_cast<const f32x4*>(src)[3];
        #pragma unroll
        for (int i = 0; i < 4; i++) Ts[nseg +      i][krow] = f2b(v0[i]);
        #pragma unroll
        for (int i = 0; i < 4; i++) Ts[nseg +  4 + i][krow] = f2b(v1[i]);
        #pragma unroll
        for (int i = 0; i < 4; i++) Ts[nseg +  8 + i][krow] = f2b(v2[i]);
        #pragma unroll
        for (int i = 0; i < 4; i++) Ts[nseg + 12 + i][krow] = f2b(v3[i]);
    }
    __syncthreads();
    {
        const int nrow = t >> 2;
        const int kseg = (t & 3) * 16;
        u32 out[8];
        #pragma unroll
        for (int c = 0; c < 8; c++)
            out[c] = (u32)Ts[nrow][kseg + 2 * c] | ((u32)Ts[nrow][kseg + 2 * c + 1] << 16);
        u16* dst = &WT[(size_t)(n0l + nrow) * K + k0 + kseg];
        *reinterpret_cast<u32x4*>(dst)     = (u32x4){out[0], out[1], out[2], out[3]};
        *reinterpret_cast<u32x4*>(dst + 8) = (u32x4){out[4], out[5], out[6], out[7]};
    }
}

// ---------------------------------------------------------------------------
// gemm_bt2: C = A[M,K]@B + bias. A bf16 [m][k], BT bf16 [n][k]. Both operands
// staged via global_load_lds width=16 into LINEAR LDS (m97 structure).
// 2-barrier K-loop, BK=64.
// OUTMODE: 0 bf16 row-major, 1 fp32 row-major, 2 bf16 transposed VT[N][STOT].
// ---------------------------------------------------------------------------
template<int OUTMODE, int MT>
__global__ __launch_bounds__(256, 2) void gemm_bt2_kernel(
    const u16* __restrict__ A, const u16* __restrict__ BT,
    const float* __restrict__ bias, void* __restrict__ Cv, size_t coff,
    int K, int Ntot, int ncol0)
{
    constexpr int MI  = MT / 32;   // acc row-tiles per wave
    constexpr int ASP = MT / 32;   // A 4KB staging spans
    __shared__ __align__(16) u16 As[MT][64];
    __shared__ __align__(16) u16 Bs[128][64];

    const int t    = threadIdx.x;
    const int lane = t & 63;
    const int wave = t >> 6;
    const int wr   = wave >> 1;
    const int wc   = wave & 1;
    const int m0   = blockIdx.x * MT;
    const int n0   = blockIdx.y * 128;
    const int fm   = lane & 15;
    const int fq   = lane >> 4;

    const int srow = t >> 3;
    const int skb  = (t & 7) * 8;

    f32x4 acc[MI][4];
    #pragma unroll
    for (int i = 0; i < MI; i++)
        #pragma unroll
        for (int j = 0; j < 4; j++)
            acc[i][j] = (f32x4){0.f, 0.f, 0.f, 0.f};

    const u16* aBase = A  + (size_t)(m0 + srow) * K + skb;
    const u16* bBase = BT + (size_t)(n0 + srow) * K + skb;
    char* asDst = (char*)&As[0][0] + (size_t)wave * 1024;   // wave-uniform
    char* bsDst = (char*)&Bs[0][0] + (size_t)wave * 1024;

    for (int k0 = 0; k0 < K; k0 += 64) {
        __syncthreads();
        #pragma unroll
        for (int s = 0; s < 4; s++)
            __builtin_amdgcn_global_load_lds(
                (gas_void*)(bBase + (size_t)(s * 32) * K + k0),
                (las_void*)(bsDst + s * 4096), 16, 0, 0);
        #pragma unroll
        for (int s = 0; s < ASP; s++)
            __builtin_amdgcn_global_load_lds(
                (gas_void*)(aBase + (size_t)(s * 32) * K + k0),
                (las_void*)(asDst + s * 4096), 16, 0, 0);
        __syncthreads();

        #pragma unroll
        for (int h = 0; h < 2; h++) {
            bf16x8 af[MI], bfr[4];
            #pragma unroll
            for (int i = 0; i < MI; i++)
                af[i] = *reinterpret_cast<const bf16x8*>(
                    &As[wr * (MT / 2) + i * 16 + fm][h * 32 + fq * 8]);
            #pragma unroll
            for (int j = 0; j < 4; j++)
                bfr[j] = *reinterpret_cast<const bf16x8*>(
                    &Bs[wc * 64 + j * 16 + fm][h * 32 + fq * 8]);
            #pragma unroll
            for (int i = 0; i < MI; i++)
                #pragma unroll
                for (int j = 0; j < 4; j++)
                    acc[i][j] = __builtin_amdgcn_mfma_f32_16x16x32_bf16(af[i], bfr[j], acc[i][j], 0, 0, 0);
        }
    }

    #pragma unroll
    for (int i = 0; i < MI; i++) {
        #pragma unroll
        for (int j = 0; j < 4; j++) {
            int col = ncol0 + n0 + wc * 64 + j * 16 + fm;
            float bb = bias[col];
            if (OUTMODE == 2) {
                int tok = (int)coff + m0 + wr * (MT / 2) + i * 16 + fq * 4;
                u32x2 pr = {pk2(acc[i][j][0] + bb, acc[i][j][1] + bb),
                            pk2(acc[i][j][2] + bb, acc[i][j][3] + bb)};
                *reinterpret_cast<u32x2*>(&((u16*)Cv)[(size_t)col * STOT + tok]) = pr;
            } else {
                #pragma unroll
                for (int r = 0; r < 4; r++) {
                    int row = m0 + wr * (MT / 2) + i * 16 + fq * 4 + r;
                    size_t idx = coff + (size_t)row * Ntot + col;
                    float val = acc[i][j][r] + bb;
                    if (OUTMODE == 1) ((float*)Cv)[idx] = val;
                    else              ((u16*)Cv)[idx]   = f2b(val);
                }
            }
        }
    }
}

// ---------------------------------------------------------------------------
// gemm_bt: verified R2 path (reg-staged, padded LDS). Fallback tier.
// ---------------------------------------------------------------------------
template<int AF32, int OUTMODE, int MT>
__global__ __launch_bounds__(256, 2) void gemm_bt_kernel(
    const void* __restrict__ Av, const u16* __restrict__ BT,
    const float* __restrict__ bias, void* __restrict__ Cv, size_t coff,
    int M, int K, int Ntot, int ncol0)
{
    constexpr int MI = MT / 32;
    constexpr int ASEGN = (MT == 128) ? 32 : 16;
    __shared__ u16 As[MT][72];
    __shared__ u16 Bs[128][72];

    const int t    = threadIdx.x;
    const int lane = t & 63;
    const int wave = t >> 6;
    const int wr   = wave >> 1;
    const int wc   = wave & 1;
    const int m0   = blockIdx.x * MT;
    const int n0   = blockIdx.y * 128;
    const int fm   = lane & 15;
    const int fq   = lane >> 4;

    const int arow = (MT == 128) ? (t >> 1) : (t >> 2);
    const int aseg = (MT == 128) ? ((t & 1) * 32) : ((t & 3) * 16);
    const int brow = t >> 1;
    const int bseg = (t & 1) * 32;

    f32x4 acc[MI][4];
    #pragma unroll
    for (int i = 0; i < MI; i++)
        #pragma unroll
        for (int j = 0; j < 4; j++)
            acc[i][j] = (f32x4){0.f, 0.f, 0.f, 0.f};

    for (int k0 = 0; k0 < K; k0 += 64) {
        u32 aw[ASEGN / 2];
        if (AF32) {
            const float* ap = (const float*)Av + (size_t)(m0 + arow) * K + k0 + aseg;
            #pragma unroll
            for (int c = 0; c < ASEGN / 4; c++) {
                f32x4 x = reinterpret_cast<const f32x4*>(ap)[c];
                aw[2 * c]     = pk2(x[0], x[1]);
                aw[2 * c + 1] = pk2(x[2], x[3]);
            }
        } else {
            const u32x4* ap = reinterpret_cast<const u32x4*>(
                (const u16*)Av + (size_t)(m0 + arow) * K + k0 + aseg);
            #pragma unroll
            for (int c = 0; c < ASEGN / 8; c++) {
                u32x4 x = ap[c];
                aw[4 * c] = x[0]; aw[4 * c + 1] = x[1];
                aw[4 * c + 2] = x[2]; aw[4 * c + 3] = x[3];
            }
        }
        u32x4 bw[4];
        {
            const u32x4* bp = reinterpret_cast<const u32x4*>(
                &BT[(size_t)(n0 + brow) * K + k0 + bseg]);
            bw[0] = bp[0]; bw[1] = bp[1]; bw[2] = bp[2]; bw[3] = bp[3];
        }
        __syncthreads();
        #pragma unroll
        for (int c = 0; c < ASEGN / 8; c++)
            *reinterpret_cast<u32x4*>(&As[arow][aseg + c * 8]) =
                (u32x4){aw[4 * c], aw[4 * c + 1], aw[4 * c + 2], aw[4 * c + 3]};
        #pragma unroll
        for (int c = 0; c < 4; c++)
            *reinterpret_cast<u32x4*>(&Bs[brow][bseg + c * 8]) = bw[c];
        __syncthreads();

        #pragma unroll
        for (int h = 0; h < 2; h++) {
            bf16x8 af[MI], bfr[4];
            #pragma unroll
            for (int i = 0; i < MI; i++)
                af[i] = *reinterpret_cast<const bf16x8*>(
                    &As[wr * (MT / 2) + i * 16 + fm][h * 32 + fq * 8]);
            #pragma unroll
            for (int j = 0; j < 4; j++)
                bfr[j] = *reinterpret_cast<const bf16x8*>(
                    &Bs[wc * 64 + j * 16 + fm][h * 32 + fq * 8]);
            #pragma unroll
            for (int i = 0; i < MI; i++)
                #pragma unroll
                for (int j = 0; j < 4; j++)
                    acc[i][j] = __builtin_amdgcn_mfma_f32_16x16x32_bf16(af[i], bfr[j], acc[i][j], 0, 0, 0);
        }
    }

    #pragma unroll
    for (int i = 0; i < MI; i++) {
        #pragma unroll
        for (int j = 0; j < 4; j++) {
            int col = ncol0 + n0 + wc * 64 + j * 16 + fm;
            float bb = bias[col];
            if (OUTMODE == 2) {
                int tok = (int)coff + m0 + wr * (MT / 2) + i * 16 + fq * 4;
                u32x2 pr = {pk2(acc[i][j][0] + bb, acc[i][j][1] + bb),
                            pk2(acc[i][j][2] + bb, acc[i][j][3] + bb)};
                *reinterpret_cast<u32x2*>(&((u16*)Cv)[(size_t)col * STOT + tok]) = pr;
            } else {
                #pragma unroll
                for (int r = 0; r < 4; r++) {
                    int row = m0 + wr * (MT / 2) + i * 16 + fq * 4 + r;
                    size_t idx = coff + (size_t)row * Ntot + col;
                    float val = acc[i][j][r] + bb;
                    if (OUTMODE == 1) ((float*)Cv)[idx] = val;
                    else              ((u16*)Cv)[idx]   = f2b(val);
                }
            }
        }
    }
}

// ---------------------------------------------------------------------------
// Fallback GEMM (fp32 W, scalar staging, BK=32) — only if ws too small.
// ---------------------------------------------------------------------------
template<int AF32, int OUTMODE>
__global__ __launch_bounds__(256, 2) void gemm_bias_kernel(
    const void* __restrict__ Av, const float* __restrict__ W,
    const float* __restrict__ bias, void* __restrict__ Cv, size_t coff,
    int M, int K, int N)
{
    __shared__ u16 As[128][40];
    __shared__ u16 Bs[128][40];

    const int t    = threadIdx.x;
    const int lane = t & 63;
    const int wave = t >> 6;
    const int wr   = wave >> 1;
    const int wc   = wave & 1;
    const int m0   = blockIdx.x * 128;
    const int n0   = blockIdx.y * 128;
    const int fm   = lane & 15;
    const int fq   = lane >> 4;

    const int arow = t >> 1;
    const int akg  = (t & 1) * 16;
    const int bn   = t >> 1;
    const int bkg  = (t & 1) * 16;

    f32x4 acc[4][4];
    #pragma unroll
    for (int i = 0; i < 4; i++)
        #pragma unroll
        for (int j = 0; j < 4; j++)
            acc[i][j] = (f32x4){0.f, 0.f, 0.f, 0.f};

    for (int k0 = 0; k0 < K; k0 += 32) {
        u32x4 a0, a1;
        if (AF32) {
            const f32x4* p = reinterpret_cast<const f32x4*>(
                (const float*)Av + (size_t)(m0 + arow) * K + k0 + akg);
            f32x4 x0 = p[0], x1 = p[1], x2 = p[2], x3 = p[3];
            a0 = (u32x4){pk2(x0[0], x0[1]), pk2(x0[2], x0[3]),
                         pk2(x1[0], x1[1]), pk2(x1[2], x1[3])};
            a1 = (u32x4){pk2(x2[0], x2[1]), pk2(x2[2], x2[3]),
                         pk2(x3[0], x3[1]), pk2(x3[2], x3[3])};
        } else {
            const u32x4* p = reinterpret_cast<const u32x4*>(
                (const u16*)Av + (size_t)(m0 + arow) * K + k0 + akg);
            a0 = p[0]; a1 = p[1];
        }
        float wv[16];
        #pragma unroll
        for (int j = 0; j < 16; j++)
            wv[j] = W[(size_t)(k0 + bkg + j) * N + n0 + bn];
        u32x4 b0, b1;
        #pragma unroll
        for (int j = 0; j < 4; j++) {
            b0[j] = pk2(wv[2 * j],     wv[2 * j + 1]);
            b1[j] = pk2(wv[8 + 2 * j], wv[8 + 2 * j + 1]);
        }
        __syncthreads();
        *reinterpret_cast<u32x4*>(&As[arow][akg])     = a0;
        *reinterpret_cast<u32x4*>(&As[arow][akg + 8]) = a1;
        *reinterpret_cast<u32x4*>(&Bs[bn][bkg])       = b0;
        *reinterpret_cast<u32x4*>(&Bs[bn][bkg + 8])   = b1;
        __syncthreads();

        bf16x8 af[4], bfr[4];
        #pragma unroll
        for (int i = 0; i < 4; i++)
            af[i] = *reinterpret_cast<const bf16x8*>(&As[wr * 64 + i * 16 + fm][fq * 8]);
        #pragma unroll
        for (int j = 0; j < 4; j++)
            bfr[j] = *reinterpret_cast<const bf16x8*>(&Bs[wc * 64 + j * 16 + fm][fq * 8]);
        #pragma unroll
        for (int i = 0; i < 4; i++)
            #pragma unroll
            for (int j = 0; j < 4; j++)
                acc[i][j] = __builtin_amdgcn_mfma_f32_16x16x32_bf16(af[i], bfr[j], acc[i][j], 0, 0, 0);
    }

    #pragma unroll
    for (int i = 0; i < 4; i++) {
        #pragma unroll
        for (int j = 0; j < 4; j++) {
            int col = n0 + wc * 64 + j * 16 + fm;
            float bb = bias[col];
            if (OUTMODE == 2) {
                int tok = (int)coff + m0 + wr * 64 + i * 16 + fq * 4;
                u32x2 pr = {pk2(acc[i][j][0] + bb, acc[i][j][1] + bb),
                            pk2(acc[i][j][2] + bb, acc[i][j][3] + bb)};
                *reinterpret_cast<u32x2*>(&((u16*)Cv)[(size_t)col * STOT + tok]) = pr;
            } else {
                #pragma unroll
                for (int r = 0; r < 4; r++) {
                    int row = m0 + wr * 64 + i * 16 + fq * 4 + r;
                    size_t idx = coff + (size_t)row * N + col;
                    float val = acc[i][j][r] + bb;
                    if (OUTMODE == 1) ((float*)Cv)[idx] = val;
                    else              ((u16*)Cv)[idx]   = f2b(val);
                }
            }
        }
    }
}

// ---------------------------------------------------------------------------
// Fused per-head RMSNorm + RoPE, in place. 4 waves/block, one token each.
// ---------------------------------------------------------------------------
__global__ __launch_bounds__(256) void rmsrope_kernel(
    u16* __restrict__ Qf, u16* __restrict__ Kf,
    const float* __restrict__ nq, const float* __restrict__ nk,
    const float* __restrict__ naq, const float* __restrict__ nak,
    const float* __restrict__ cosb, const float* __restrict__ sinb)
{
    const int h     = blockIdx.x;
    const int tok   = blockIdx.y * 4 + (threadIdx.x >> 6);
    const int which = blockIdx.z;
    u16* buf = which ? Kf : Qf;
    const float* nw = (tok < TXT) ? (which ? nak : naq) : (which ? nk : nq);
    const int t = threadIdx.x & 63;
    const size_t base = (size_t)tok * DIM + h * HD + 2 * t;

    u32 pr = *reinterpret_cast<const u32*>(&buf[base]);
    float x0 = b2f((u16)(pr & 0xFFFF));
    float x1 = b2f((u16)(pr >> 16));

    float ss = x0 * x0 + x1 * x1;
    #pragma unroll
    for (int off = 32; off; off >>= 1) ss += __shfl_xor(ss, off);
    float r = rsqrtf(ss * (1.0f / 128.0f) + 1e-6f);

    float y0 = x0 * r * nw[2 * t];
    float y1 = x1 * r * nw[2 * t + 1];
    float c0 = cosb[tok * HD + 2 * t];
    float c1 = cosb[tok * HD + 2 * t + 1];
    float s0 = sinb[tok * HD + 2 * t];
    float s1 = sinb[tok * HD + 2 * t + 1];
    float o0 = y0 * c0 - y1 * s0;
    float o1 = y1 * c1 + y0 * s1;
    *reinterpret_cast<u32*>(&buf[base]) = pk2(o0, o1);
}

// ---------------------------------------------------------------------------
// MFMA flash attention (M_rep=2, verified R3 body). R6 = R3 + ONLY the XCD
// chunk swizzle (bisection: R4's other change, gemm_qkv, is removed this
// round). Swizzle: 480 blocks = 8 x 60; XCD x gets contiguous ids
// [x*60, x*60+60) = 3 heads, whose KV (3 x 1.25MB) fits its private 4MB L2.
// ---------------------------------------------------------------------------
__global__ __launch_bounds__(256, 2) void attn_kernel(
    const u16* __restrict__ Qf, const u16* __restrict__ Kf,
    const u16* __restrict__ VTg, u16* __restrict__ AO)
{
    __shared__ u16 Ks[64][136];
    __shared__ u16 VTs[128][72];
    __shared__ u16 Ps[4][32][72];

    const int t    = threadIdx.x;
    const int w    = t >> 6;
    const int lane = t & 63;
    const int col  = lane & 15;
    const int quad = lane >> 4;

    // XCD-chunked remap: flat dispatch id -> contiguous per-XCD chunk
    const int flat = blockIdx.x + blockIdx.y * 20;      // 480 = 8*60 exact
    const int rm   = (flat & 7) * 60 + (flat >> 3);
    const int h    = rm / 20;
    const int q0   = (rm % 20) * 128;

    const bool is_ref = (q0 >= TXT) && (q0 < TXT + 512);
    const int ks = is_ref ? TXT : 0;
    const int ke = is_ref ? (TXT + 512) : STOT;

    bf16x8 Qfrag[2][4];
    #pragma unroll
    for (int s = 0; s < 2; s++) {
        const size_t qbase = (size_t)(q0 + w * 32 + s * 16 + col) * DIM + h * HD;
        #pragma unroll
        for (int c = 0; c < 4; c++)
            Qfrag[s][c] = *reinterpret_cast<const bf16x8*>(&Qf[qbase + c * 32 + quad * 8]);
    }

    f32x4 O[2][8];
    f32x4 m[2], l[2];
    #pragma unroll
    for (int s = 0; s < 2; s++) {
        #pragma unroll
        for (int dt = 0; dt < 8; dt++) O[s][dt] = (f32x4){0.f, 0.f, 0.f, 0.f};
        m[s] = (f32x4){-1e30f, -1e30f, -1e30f, -1e30f};
        l[s] = (f32x4){0.f, 0.f, 0.f, 0.f};
    }

    const int krow = t >> 2, kseg = t & 3;
    const int vrow = t >> 1, vseg = t & 1;

    u32x4 kreg[4], vreg[4];
    {
        const u32x4* src = reinterpret_cast<const u32x4*>(
            &Kf[(size_t)(ks + krow) * DIM + h * HD + kseg * 32]);
        kreg[0] = src[0]; kreg[1] = src[1]; kreg[2] = src[2]; kreg[3] = src[3];
        const u32x4* vsrc = reinterpret_cast<const u32x4*>(
            &VTg[(size_t)(h * HD + vrow) * STOT + ks + vseg * 32]);
        vreg[0] = vsrc[0]; vreg[1] = vsrc[1]; vreg[2] = vsrc[2]; vreg[3] = vsrc[3];
    }

    for (int k0 = ks; k0 < ke; k0 += 64) {
        __syncthreads();
        {
            u32x4* dst = reinterpret_cast<u32x4*>(&Ks[krow][kseg * 32]);
            dst[0] = kreg[0]; dst[1] = kreg[1]; dst[2] = kreg[2]; dst[3] = kreg[3];
            u32x4* vdst = reinterpret_cast<u32x4*>(&VTs[vrow][vseg * 32]);
            vdst[0] = vreg[0]; vdst[1] = vreg[1]; vdst[2] = vreg[2]; vdst[3] = vreg[3];
        }
        __syncthreads();

        if (k0 + 64 < ke) {
            const u32x4* src = reinterpret_cast<const u32x4*>(
                &Kf[(size_t)(k0 + 64 + krow) * DIM + h * HD + kseg * 32]);
            kreg[0] = src[0]; kreg[1] = src[1]; kreg[2] = src[2]; kreg[3] = src[3];
            const u32x4* vsrc = reinterpret_cast<const u32x4*>(
                &VTg[(size_t)(h * HD + vrow) * STOT + k0 + 64 + vseg * 32]);
            vreg[0] = vsrc[0]; vreg[1] = vsrc[1]; vreg[2] = vsrc[2]; vreg[3] = vsrc[3];
        }

        f32x4 sc[2][4];
        #pragma unroll
        for (int kt = 0; kt < 4; kt++) {
            f32x4 a0 = (f32x4){0.f, 0.f, 0.f, 0.f};
            f32x4 a1 = (f32x4){0.f, 0.f, 0.f, 0.f};
            #pragma unroll
            for (int c = 0; c < 4; c++) {
                bf16x8 kf = *reinterpret_cast<const bf16x8*>(
                    &Ks[kt * 16 + col][c * 32 + quad * 8]);
                a0 = __builtin_amdgcn_mfma_f32_16x16x32_bf16(Qfrag[0][c], kf, a0, 0, 0, 0);
                a1 = __builtin_amdgcn_mfma_f32_16x16x32_bf16(Qfrag[1][c], kf, a1, 0, 0, 0);
            }
            sc[0][kt] = a0 * SOFTMAX_SCALE;
            sc[1][kt] = a1 * SOFTMAX_SCALE;
        }

        #pragma unroll
        for (int s = 0; s < 2; s++) {
            f32x4 tmax = max4(max4(sc[s][0], sc[s][1]), max4(sc[s][2], sc[s][3]));
            tmax = max4(tmax, shfl_xor4(tmax, 1));
            tmax = max4(tmax, shfl_xor4(tmax, 2));
            tmax = max4(tmax, shfl_xor4(tmax, 4));
            tmax = max4(tmax, shfl_xor4(tmax, 8));
            const bool ok = (tmax[0] - m[s][0] <= 8.0f) && (tmax[1] - m[s][1] <= 8.0f) &&
                            (tmax[2] - m[s][2] <= 8.0f) && (tmax[3] - m[s][3] <= 8.0f);
            const bool skip = __all(ok);
            f32x4 mnew = skip ? m[s] : max4(m[s], tmax);

            f32x4 rowsum = (f32x4){0.f, 0.f, 0.f, 0.f};
            f32x4 p[4];
            #pragma unroll
            for (int kt = 0; kt < 4; kt++)
                #pragma unroll
                for (int r = 0; r < 4; r++) {
                    p[kt][r] = __expf(sc[s][kt][r] - mnew[r]);
                    rowsum[r] += p[kt][r];
                }
            rowsum += shfl_xor4(rowsum, 1);
            rowsum += shfl_xor4(rowsum, 2);
            rowsum += shfl_xor4(rowsum, 4);
            rowsum += shfl_xor4(rowsum, 8);

            if (skip) {
                #pragma unroll
                for (int r = 0; r < 4; r++) l[s][r] += rowsum[r];
            } else {
                f32x4 alpha;
                #pragma unroll
                for (int r = 0; r < 4; r++) alpha[r] = __expf(m[s][r] - mnew[r]);
                #pragma unroll
                for (int r = 0; r < 4; r++) l[s][r] = l[s][r] * alpha[r] + rowsum[r];
                m[s] = mnew;
                #pragma unroll
                for (int dt = 0; dt < 8; dt++)
                    #pragma unroll
                    for (int r = 0; r < 4; r++) O[s][dt][r] *= alpha[r];
            }

            #pragma unroll
            for (int r = 0; r < 4; r++) {
                u32 w01 = pk2(p[0][r], p[1][r]);
                u32 w23 = pk2(p[2][r], p[3][r]);
                u16* prow = &Ps[w][s * 16 + quad * 4 + r][0];
                prow[col]      = (u16)(w01 & 0xFFFFu);
                prow[col + 16] = (u16)(w01 >> 16);
                prow[col + 32] = (u16)(w23 & 0xFFFFu);
                prow[col + 48] = (u16)(w23 >> 16);
            }
        }

        __builtin_amdgcn_s_setprio(1);
        #pragma unroll
        for (int c = 0; c < 2; c++) {
            bf16x8 pf0 = *reinterpret_cast<const bf16x8*>(
                &Ps[w][col][c * 32 + quad * 8]);
            bf16x8 pf1 = *reinterpret_cast<const bf16x8*>(
                &Ps[w][16 + col][c * 32 + quad * 8]);
            #pragma unroll
            for (int dt = 0; dt < 8; dt++) {
                bf16x8 vf = *reinterpret_cast<const bf16x8*>(
                    &VTs[dt * 16 + col][c * 32 + quad * 8]);
                O[0][dt] = __builtin_amdgcn_mfma_f32_16x16x32_bf16(pf0, vf, O[0][dt], 0, 0, 0);
                O[1][dt] = __builtin_amdgcn_mfma_f32_16x16x32_bf16(pf1, vf, O[1][dt], 0, 0, 0);
            }
        }
        __builtin_amdgcn_s_setprio(0);
    }

    #pragma unroll
    for (int s = 0; s < 2; s++) {
        f32x4 inv;
        #pragma unroll
        for (int r = 0; r < 4; r++) inv[r] = 1.0f / l[s][r];
        #pragma unroll
        for (int dt = 0; dt < 8; dt++)
            #pragma unroll
            for (int r = 0; r < 4; r++)
                AO[(size_t)(q0 + w * 32 + s * 16 + quad * 4 + r) * DIM + h * HD + dt * 16 + col] =
                    f2b(O[s][dt][r] * inv[r]);
    }
}

// ---------------------------------------------------------------------------
// Buffer plan:
//   Qf/AO = d_ws                  [STOT*DIM bf16] 15.7 MB
//   WT    = d_ws + QFB            [DIM*DIM bf16]  18.9 MB (tiered)
//   Xbf   = d_ws + QFB + WTF      [STOT*DIM bf16] 15.7 MB (top tier only)
//   Kf    = d_out lower           [STOT*DIM bf16]
//   VTg   = d_out upper           [DIM][STOT] bf16
// ---------------------------------------------------------------------------
extern "C" void kernel_launch(void* const* d_in, const int* in_sizes, int n_in,
                              void* d_out, int out_size, void* d_ws, size_t ws_size,
                              hipStream_t stream)
{
    const void*  hs  = d_in[0];
    const void*  enc = d_in[1];
    const float* rc  = (const float*)d_in[2];
    const float* rs  = (const float*)d_in[3];
    const float* wq  = (const float*)d_in[4];  const float* bq  = (const float*)d_in[5];
    const float* wk  = (const float*)d_in[6];  const float* bk  = (const float*)d_in[7];
    const float* wv  = (const float*)d_in[8];  const float* bv  = (const float*)d_in[9];
    const float* waq = (const float*)d_in[10]; const float* baq = (const float*)d_in[11];
    const float* wak = (const float*)d_in[12]; const float* bak = (const float*)d_in[13];
    const float* wav = (const float*)d_in[14]; const float* bav = (const float*)d_in[15];
    const float* nq  = (const float*)d_in[16]; const float* nk  = (const float*)d_in[17];
    const float* naq = (const float*)d_in[18]; const float* nak = (const float*)d_in[19];
    const float* wo  = (const float*)d_in[20]; const float* bo  = (const float*)d_in[21];
    const float* wao = (const float*)d_in[22]; const float* bao = (const float*)d_in[23];

    const size_t QFB = (size_t)STOT * DIM * sizeof(u16);      // 15,728,640
    const size_t WTF = (size_t)DIM * DIM * sizeof(u16);       // 18,874,368
    u16* Qf  = (u16*)d_ws;
    u16* WT  = (u16*)((char*)d_ws + QFB);
    u16* Xbf = (u16*)((char*)d_ws + QFB + WTF);
    u16* Kf  = (u16*)d_out;
    u16* VTg = (u16*)d_out + (size_t)STOT * DIM;
    u16* AO  = Qf;

    dim3 blk(256);
    dim3 tgrid(DIM / 64, DIM / 64);

    if (ws_size >= 2 * QFB + WTF) {
        // ---- fast path: bf16 A + global_load_lds GEMMs (verified R3) ----
        convert_bf16_kernel<<<dim3((SEQ * DIM / 8) / 256), blk, 0, stream>>>(
            (const float*)hs, Xbf + (size_t)TXT * DIM, SEQ * DIM / 8);
        convert_bf16_kernel<<<dim3((TXT * DIM / 8) / 256), blk, 0, stream>>>(
            (const float*)enc, Xbf, TXT * DIM / 8);
        #define RUN2(MODE_, MT_, Aptr, Wptr, Bias, Cptr, Coff, M_)                   \
            transpose_w_kernel<<<tgrid, blk, 0, stream>>>(Wptr, WT, DIM, DIM, 0);    \
            gemm_bt2_kernel<MODE_, MT_><<<dim3((M_) / MT_, DIM / 128), blk, 0, stream>>>( \
                Aptr, WT, Bias, Cptr, Coff, DIM, DIM, 0);
        RUN2(0, 128, Xbf + (size_t)TXT * DIM, wq,  bq,  Qf,  (size_t)TXT * DIM, SEQ)
        RUN2(0, 128, Xbf + (size_t)TXT * DIM, wk,  bk,  Kf,  (size_t)TXT * DIM, SEQ)
        RUN2(2, 128, Xbf + (size_t)TXT * DIM, wv,  bv,  VTg, (size_t)TXT,       SEQ)
        RUN2(0, 64,  Xbf,                     waq, baq, Qf,  0,                 TXT)
        RUN2(0, 64,  Xbf,                     wak, bak, Kf,  0,                 TXT)
        RUN2(2, 64,  Xbf,                     wav, bav, VTg, 0,                 TXT)
        rmsrope_kernel<<<dim3(NH, STOT / 4, 2), blk, 0, stream>>>(Qf, Kf, nq, nk, naq, nak, rc, rs);
        attn_kernel<<<dim3(STOT / 128, NH), blk, 0, stream>>>(Qf, Kf, VTg, AO);
        RUN2(1, 128, AO + (size_t)TXT * DIM, wo,  bo,  d_out, 0,                 SEQ)
        RUN2(1, 64,  AO,                     wao, bao, d_out, (size_t)SEQ * DIM, TXT)
        #undef RUN2
        return;
    }

    int nchunk;
    if      (ws_size >= QFB + WTF)     nchunk = DIM;
    else if (ws_size >= QFB + WTF / 2) nchunk = DIM / 2;
    else                               nchunk = 0;

    if (nchunk > 0) {
        dim3 tgrid2(DIM / 64, nchunk / 64);
        #define RUN_GEMM(AF32_, MODE_, MT_, Aptr, Wptr, Bias, Cptr, Coff, M_)     \
            for (int nb = 0; nb < DIM; nb += nchunk) {                            \
                transpose_w_kernel<<<tgrid2, blk, 0, stream>>>(Wptr, WT, DIM, DIM, nb); \
                gemm_bt_kernel<AF32_, MODE_, MT_><<<dim3((M_) / MT_, nchunk / 128), blk, 0, stream>>>( \
                    Aptr, WT, Bias, Cptr, Coff, M_, DIM, DIM, nb);                \
            }
        RUN_GEMM(1, 0, 128, hs,  wq,  bq,  Qf,  (size_t)TXT * DIM, SEQ)
        RUN_GEMM(1, 0, 128, hs,  wk,  bk,  Kf,  (size_t)TXT * DIM, SEQ)
        RUN_GEMM(1, 2, 128, hs,  wv,  bv,  VTg, (size_t)TXT,       SEQ)
        RUN_GEMM(1, 0, 64,  enc, waq, baq, Qf,  0,                 TXT)
        RUN_GEMM(1, 0, 64,  enc, wak, bak, Kf,  0,                 TXT)
        RUN_GEMM(1, 2, 64,  enc, wav, bav, VTg, 0,                 TXT)
        rmsrope_kernel<<<dim3(NH, STOT / 4, 2), blk, 0, stream>>>(Qf, Kf, nq, nk, naq, nak, rc, rs);
        attn_kernel<<<dim3(STOT / 128, NH), blk, 0, stream>>>(Qf, Kf, VTg, AO);
        RUN_GEMM(0, 1, 128, AO + (size_t)TXT * DIM, wo,  bo,  d_out, 0,                 SEQ)
        RUN_GEMM(0, 1, 64,  AO,                     wao, bao, d_out, (size_t)SEQ * DIM, TXT)
        #undef RUN_GEMM
    } else {
        gemm_bias_kernel<1,0><<<dim3(SEQ / 128, DIM / 128), blk, 0, stream>>>(hs, wq, bq, Qf, (size_t)TXT * DIM, SEQ, DIM, DIM);
        gemm_bias_kernel<1,0><<<dim3(SEQ / 128, DIM / 128), blk, 0, stream>>>(hs, wk, bk, Kf, (size_t)TXT * DIM, SEQ, DIM, DIM);
        gemm_bias_kernel<1,2><<<dim3(SEQ / 128, DIM / 128), blk, 0, stream>>>(hs, wv, bv, VTg, (size_t)TXT, SEQ, DIM, DIM);
        gemm_bias_kernel<1,0><<<dim3(TXT / 128, DIM / 128), blk, 0, stream>>>(enc, waq, baq, Qf, 0, TXT, DIM, DIM);
        gemm_bias_kernel<1,0><<<dim3(TXT / 128, DIM / 128), blk, 0, stream>>>(enc, wak, bak, Kf, 0, TXT, DIM, DIM);
        gemm_bias_kernel<1,2><<<dim3(TXT / 128, DIM / 128), blk, 0, stream>>>(enc, wav, bav, VTg, 0, TXT, DIM, DIM);
        rmsrope_kernel<<<dim3(NH, STOT / 4, 2), blk, 0, stream>>>(Qf, Kf, nq, nk, naq, nak, rc, rs);
        attn_kernel<<<dim3(STOT / 128, NH), blk, 0, stream>>>(Qf, Kf, VTg, AO);
        gemm_bias_kernel<0,1><<<dim3(SEQ / 128, DIM / 128), blk, 0, stream>>>(AO + (size_t)TXT * DIM, wo, bo, d_out, 0, SEQ, DIM, DIM);
        gemm_bias_kernel<0,1><<<dim3(TXT / 128, DIM / 128), blk, 0, stream>>>(AO, wao, bao, d_out, (size_t)SEQ * DIM, TXT, DIM, DIM);
    }
}

// Round 8
// 951.346 us; speedup vs baseline: 1.3716x; 1.0861x over previous
//
#include <hip/hip_runtime.h>
#include <hip/hip_bf16.h>

typedef unsigned short u16;
typedef unsigned int u32;
typedef __bf16 bf16x8 __attribute__((ext_vector_type(8)));
typedef float f32x4 __attribute__((ext_vector_type(4)));
typedef unsigned int u32x4 __attribute__((ext_vector_type(4)));
typedef unsigned int u32x2 __attribute__((ext_vector_type(2)));

#define TXT 512
#define SEQ 2048
#define STOT 2560
#define DIM 3072
#define NH 24
#define HD 128
#define SOFTMAX_SCALE 0.08838834764831845f

typedef const __attribute__((address_space(1))) void gas_void;
typedef __attribute__((address_space(3))) void las_void;

__device__ __forceinline__ float b2f(u16 u) {
    union { u32 i; float f; } c; c.i = ((u32)u) << 16; return c.f;
}
__device__ __forceinline__ u16 f2b(float f) {
    union { float f; u32 i; } c; c.f = f;
    u32 x = c.i;
    return (u16)((x + 0x7FFFu + ((x >> 16) & 1u)) >> 16);
}
__device__ __forceinline__ u32 pk2(float a, float b) {
    __hip_bfloat162 h = __float22bfloat162_rn(make_float2(a, b));
    return *reinterpret_cast<u32*>(&h);
}
__device__ __forceinline__ f32x4 max4(f32x4 a, f32x4 b) {
    return (f32x4){fmaxf(a[0], b[0]), fmaxf(a[1], b[1]),
                   fmaxf(a[2], b[2]), fmaxf(a[3], b[3])};
}
__device__ __forceinline__ f32x4 shfl_xor4(f32x4 v, int mask) {
    return (f32x4){__shfl_xor(v[0], mask), __shfl_xor(v[1], mask),
                   __shfl_xor(v[2], mask), __shfl_xor(v[3], mask)};
}

// ---------------------------------------------------------------------------
// convert_bf16: fp32 -> bf16, 8 elems/thread.
// ---------------------------------------------------------------------------
__global__ __launch_bounds__(256) void convert_bf16_kernel(
    const float* __restrict__ src, u16* __restrict__ dst, int n8)
{
    int i = blockIdx.x * 256 + threadIdx.x;
    if (i < n8) {
        const f32x4* p = reinterpret_cast<const f32x4*>(src + (size_t)i * 8);
        f32x4 a = p[0], b = p[1];
        u32x4 o = {pk2(a[0], a[1]), pk2(a[2], a[3]), pk2(b[0], b[1]), pk2(b[2], b[3])};
        *reinterpret_cast<u32x4*>(dst + (size_t)i * 8) = o;
    }
}

// ---------------------------------------------------------------------------
// transpose_w: W fp32 [K][Ntot] -> WT bf16 [ncols][K] (ncols from nbase).
// ---------------------------------------------------------------------------
__global__ __launch_bounds__(256, 2) void transpose_w_kernel(
    const float* __restrict__ W, u16* __restrict__ WT,
    int K, int Ntot, int nbase)
{
    __shared__ u16 Ts[64][66];
    const int t   = threadIdx.x;
    const int k0  = blockIdx.x * 64;
    const int n0l = blockIdx.y * 64;
    const int n0g = nbase + n0l;

    {
        const int krow = t >> 2;
        const int nseg = (t & 3) * 16;
        const float* src = &W[(size_t)(k0 + krow) * Ntot + n0g + nseg];
        f32x4 v0 = reinterpret_cast<const f32x4*>(src)[0];
        f32x4 v1 = reinterpret_cast<const f32x4*>(src)[1];
        f32x4 v2 = reinterpret_cast<const f32x4*>(src)[2];
        f32x4 v3 = reinterpret_cast<const f32x4*>(src)[3];
        #pragma unroll
        for (int i = 0; i < 4; i++) Ts[nseg +      i][krow] = f2b(v0[i]);
        #pragma unroll
        for (int i = 0; i < 4; i++) Ts[nseg +  4 + i][krow] = f2b(v1[i]);
        #pragma unroll
        for (int i = 0; i < 4; i++) Ts[nseg +  8 + i][krow] = f2b(v2[i]);
        #pragma unroll
        for (int i = 0; i < 4; i++) Ts[nseg + 12 + i][krow] = f2b(v3[i]);
    }
    __syncthreads();
    {
        const int nrow = t >> 2;
        const int kseg = (t & 3) * 16;
        u32 out[8];
        #pragma unroll
        for (int c = 0; c < 8; c++)
            out[c] = (u32)Ts[nrow][kseg + 2 * c] | ((u32)Ts[nrow][kseg + 2 * c + 1] << 16);
        u16* dst = &WT[(size_t)(n0l + nrow) * K + k0 + kseg];
        *reinterpret_cast<u32x4*>(dst)     = (u32x4){out[0], out[1], out[2], out[3]};
        *reinterpret_cast<u32x4*>(dst + 8) = (u32x4){out[4], out[5], out[6], out[7]};
    }
}

// ---------------------------------------------------------------------------
// gemm_bt2: C = A[M,K]@B + bias. A bf16 [m][k], BT bf16 [n][k]. Both operands
// staged via global_load_lds width=16 into LINEAR LDS (m97 structure).
// 2-barrier K-loop, BK=64. BYTE-IDENTICAL to the R3/R6-verified kernel.
// Used for the merged-QK launch purely via arguments: BT=[wq^T|wk^T] (6144
// rows), grid (M/MT, 48), Ntot=6144, Cv=QK2 interleaved [tok][6144].
// OUTMODE: 0 bf16 row-major, 1 fp32 row-major, 2 bf16 transposed VT[N][STOT].
// ---------------------------------------------------------------------------
template<int OUTMODE, int MT>
__global__ __launch_bounds__(256, 2) void gemm_bt2_kernel(
    const u16* __restrict__ A, const u16* __restrict__ BT,
    const float* __restrict__ bias, void* __restrict__ Cv, size_t coff,
    int K, int Ntot, int ncol0)
{
    constexpr int MI  = MT / 32;   // acc row-tiles per wave
    constexpr int ASP = MT / 32;   // A 4KB staging spans
    __shared__ __align__(16) u16 As[MT][64];
    __shared__ __align__(16) u16 Bs[128][64];

    const int t    = threadIdx.x;
    const int lane = t & 63;
    const int wave = t >> 6;
    const int wr   = wave >> 1;
    const int wc   = wave & 1;
    const int m0   = blockIdx.x * MT;
    const int n0   = blockIdx.y * 128;
    const int fm   = lane & 15;
    const int fq   = lane >> 4;

    const int srow = t >> 3;
    const int skb  = (t & 7) * 8;

    f32x4 acc[MI][4];
    #pragma unroll
    for (int i = 0; i < MI; i++)
        #pragma unroll
        for (int j = 0; j < 4; j++)
            acc[i][j] = (f32x4){0.f, 0.f, 0.f, 0.f};

    const u16* aBase = A  + (size_t)(m0 + srow) * K + skb;
    const u16* bBase = BT + (size_t)(n0 + srow) * K + skb;
    char* asDst = (char*)&As[0][0] + (size_t)wave * 1024;   // wave-uniform
    char* bsDst = (char*)&Bs[0][0] + (size_t)wave * 1024;

    for (int k0 = 0; k0 < K; k0 += 64) {
        __syncthreads();
        #pragma unroll
        for (int s = 0; s < 4; s++)
            __builtin_amdgcn_global_load_lds(
                (gas_void*)(bBase + (size_t)(s * 32) * K + k0),
                (las_void*)(bsDst + s * 4096), 16, 0, 0);
        #pragma unroll
        for (int s = 0; s < ASP; s++)
            __builtin_amdgcn_global_load_lds(
                (gas_void*)(aBase + (size_t)(s * 32) * K + k0),
                (las_void*)(asDst + s * 4096), 16, 0, 0);
        __syncthreads();

        #pragma unroll
        for (int h = 0; h < 2; h++) {
            bf16x8 af[MI], bfr[4];
            #pragma unroll
            for (int i = 0; i < MI; i++)
                af[i] = *reinterpret_cast<const bf16x8*>(
                    &As[wr * (MT / 2) + i * 16 + fm][h * 32 + fq * 8]);
            #pragma unroll
            for (int j = 0; j < 4; j++)
                bfr[j] = *reinterpret_cast<const bf16x8*>(
                    &Bs[wc * 64 + j * 16 + fm][h * 32 + fq * 8]);
            #pragma unroll
            for (int i = 0; i < MI; i++)
                #pragma unroll
                for (int j = 0; j < 4; j++)
                    acc[i][j] = __builtin_amdgcn_mfma_f32_16x16x32_bf16(af[i], bfr[j], acc[i][j], 0, 0, 0);
        }
    }

    #pragma unroll
    for (int i = 0; i < MI; i++) {
        #pragma unroll
        for (int j = 0; j < 4; j++) {
            int col = ncol0 + n0 + wc * 64 + j * 16 + fm;
            float bb = bias[col];
            if (OUTMODE == 2) {
                int tok = (int)coff + m0 + wr * (MT / 2) + i * 16 + fq * 4;
                u32x2 pr = {pk2(acc[i][j][0] + bb, acc[i][j][1] + bb),
                            pk2(acc[i][j][2] + bb, acc[i][j][3] + bb)};
                *reinterpret_cast<u32x2*>(&((u16*)Cv)[(size_t)col * STOT + tok]) = pr;
            } else {
                #pragma unroll
                for (int r = 0; r < 4; r++) {
                    int row = m0 + wr * (MT / 2) + i * 16 + fq * 4 + r;
                    size_t idx = coff + (size_t)row * Ntot + col;
                    float val = acc[i][j][r] + bb;
                    if (OUTMODE == 1) ((float*)Cv)[idx] = val;
                    else              ((u16*)Cv)[idx]   = f2b(val);
                }
            }
        }
    }
}

// ---------------------------------------------------------------------------
// gemm_bt: verified R2 path (reg-staged, padded LDS). Fallback tier.
// ---------------------------------------------------------------------------
template<int AF32, int OUTMODE, int MT>
__global__ __launch_bounds__(256, 2) void gemm_bt_kernel(
    const void* __restrict__ Av, const u16* __restrict__ BT,
    const float* __restrict__ bias, void* __restrict__ Cv, size_t coff,
    int M, int K, int Ntot, int ncol0)
{
    constexpr int MI = MT / 32;
    constexpr int ASEGN = (MT == 128) ? 32 : 16;
    __shared__ u16 As[MT][72];
    __shared__ u16 Bs[128][72];

    const int t    = threadIdx.x;
    const int lane = t & 63;
    const int wave = t >> 6;
    const int wr   = wave >> 1;
    const int wc   = wave & 1;
    const int m0   = blockIdx.x * MT;
    const int n0   = blockIdx.y * 128;
    const int fm   = lane & 15;
    const int fq   = lane >> 4;

    const int arow = (MT == 128) ? (t >> 1) : (t >> 2);
    const int aseg = (MT == 128) ? ((t & 1) * 32) : ((t & 3) * 16);
    const int brow = t >> 1;
    const int bseg = (t & 1) * 32;

    f32x4 acc[MI][4];
    #pragma unroll
    for (int i = 0; i < MI; i++)
        #pragma unroll
        for (int j = 0; j < 4; j++)
            acc[i][j] = (f32x4){0.f, 0.f, 0.f, 0.f};

    for (int k0 = 0; k0 < K; k0 += 64) {
        u32 aw[ASEGN / 2];
        if (AF32) {
            const float* ap = (const float*)Av + (size_t)(m0 + arow) * K + k0 + aseg;
            #pragma unroll
            for (int c = 0; c < ASEGN / 4; c++) {
                f32x4 x = reinterpret_cast<const f32x4*>(ap)[c];
                aw[2 * c]     = pk2(x[0], x[1]);
                aw[2 * c + 1] = pk2(x[2], x[3]);
            }
        } else {
            const u32x4* ap = reinterpret_cast<const u32x4*>(
                (const u16*)Av + (size_t)(m0 + arow) * K + k0 + aseg);
            #pragma unroll
            for (int c = 0; c < ASEGN / 8; c++) {
                u32x4 x = ap[c];
                aw[4 * c] = x[0]; aw[4 * c + 1] = x[1];
                aw[4 * c + 2] = x[2]; aw[4 * c + 3] = x[3];
            }
        }
        u32x4 bw[4];
        {
            const u32x4* bp = reinterpret_cast<const u32x4*>(
                &BT[(size_t)(n0 + brow) * K + k0 + bseg]);
            bw[0] = bp[0]; bw[1] = bp[1]; bw[2] = bp[2]; bw[3] = bp[3];
        }
        __syncthreads();
        #pragma unroll
        for (int c = 0; c < ASEGN / 8; c++)
            *reinterpret_cast<u32x4*>(&As[arow][aseg + c * 8]) =
                (u32x4){aw[4 * c], aw[4 * c + 1], aw[4 * c + 2], aw[4 * c + 3]};
        #pragma unroll
        for (int c = 0; c < 4; c++)
            *reinterpret_cast<u32x4*>(&Bs[brow][bseg + c * 8]) = bw[c];
        __syncthreads();

        #pragma unroll
        for (int h = 0; h < 2; h++) {
            bf16x8 af[MI], bfr[4];
            #pragma unroll
            for (int i = 0; i < MI; i++)
                af[i] = *reinterpret_cast<const bf16x8*>(
                    &As[wr * (MT / 2) + i * 16 + fm][h * 32 + fq * 8]);
            #pragma unroll
            for (int j = 0; j < 4; j++)
                bfr[j] = *reinterpret_cast<const bf16x8*>(
                    &Bs[wc * 64 + j * 16 + fm][h * 32 + fq * 8]);
            #pragma unroll
            for (int i = 0; i < MI; i++)
                #pragma unroll
                for (int j = 0; j < 4; j++)
                    acc[i][j] = __builtin_amdgcn_mfma_f32_16x16x32_bf16(af[i], bfr[j], acc[i][j], 0, 0, 0);
        }
    }

    #pragma unroll
    for (int i = 0; i < MI; i++) {
        #pragma unroll
        for (int j = 0; j < 4; j++) {
            int col = ncol0 + n0 + wc * 64 + j * 16 + fm;
            float bb = bias[col];
            if (OUTMODE == 2) {
                int tok = (int)coff + m0 + wr * (MT / 2) + i * 16 + fq * 4;
                u32x2 pr = {pk2(acc[i][j][0] + bb, acc[i][j][1] + bb),
                            pk2(acc[i][j][2] + bb, acc[i][j][3] + bb)};
                *reinterpret_cast<u32x2*>(&((u16*)Cv)[(size_t)col * STOT + tok]) = pr;
            } else {
                #pragma unroll
                for (int r = 0; r < 4; r++) {
                    int row = m0 + wr * (MT / 2) + i * 16 + fq * 4 + r;
                    size_t idx = coff + (size_t)row * Ntot + col;
                    float val = acc[i][j][r] + bb;
                    if (OUTMODE == 1) ((float*)Cv)[idx] = val;
                    else              ((u16*)Cv)[idx]   = f2b(val);
                }
            }
        }
    }
}

// ---------------------------------------------------------------------------
// Fallback GEMM (fp32 W, scalar staging, BK=32) — only if ws too small.
// ---------------------------------------------------------------------------
template<int AF32, int OUTMODE>
__global__ __launch_bounds__(256, 2) void gemm_bias_kernel(
    const void* __restrict__ Av, const float* __restrict__ W,
    const float* __restrict__ bias, void* __restrict__ Cv, size_t coff,
    int M, int K, int N)
{
    __shared__ u16 As[128][40];
    __shared__ u16 Bs[128][40];

    const int t    = threadIdx.x;
    const int lane = t & 63;
    const int wave = t >> 6;
    const int wr   = wave >> 1;
    const int wc   = wave & 1;
    const int m0   = blockIdx.x * 128;
    const int n0   = blockIdx.y * 128;
    const int fm   = lane & 15;
    const int fq   = lane >> 4;

    const int arow = t >> 1;
    const int akg  = (t & 1) * 16;
    const int bn   = t >> 1;
    const int bkg  = (t & 1) * 16;

    f32x4 acc[4][4];
    #pragma unroll
    for (int i = 0; i < 4; i++)
        #pragma unroll
        for (int j = 0; j < 4; j++)
            acc[i][j] = (f32x4){0.f, 0.f, 0.f, 0.f};

    for (int k0 = 0; k0 < K; k0 += 32) {
        u32x4 a0, a1;
        if (AF32) {
            const f32x4* p = reinterpret_cast<const f32x4*>(
                (const float*)Av + (size_t)(m0 + arow) * K + k0 + akg);
            f32x4 x0 = p[0], x1 = p[1], x2 = p[2], x3 = p[3];
            a0 = (u32x4){pk2(x0[0], x0[1]), pk2(x0[2], x0[3]),
                         pk2(x1[0], x1[1]), pk2(x1[2], x1[3])};
            a1 = (u32x4){pk2(x2[0], x2[1]), pk2(x2[2], x2[3]),
                         pk2(x3[0], x3[1]), pk2(x3[2], x3[3])};
        } else {
            const u32x4* p = reinterpret_cast<const u32x4*>(
                (const u16*)Av + (size_t)(m0 + arow) * K + k0 + akg);
            a0 = p[0]; a1 = p[1];
        }
        float wv[16];
        #pragma unroll
        for (int j = 0; j < 16; j++)
            wv[j] = W[(size_t)(k0 + bkg + j) * N + n0 + bn];
        u32x4 b0, b1;
        #pragma unroll
        for (int j = 0; j < 4; j++) {
            b0[j] = pk2(wv[2 * j],     wv[2 * j + 1]);
            b1[j] = pk2(wv[8 + 2 * j], wv[8 + 2 * j + 1]);
        }
        __syncthreads();
        *reinterpret_cast<u32x4*>(&As[arow][akg])     = a0;
        *reinterpret_cast<u32x4*>(&As[arow][akg + 8]) = a1;
        *reinterpret_cast<u32x4*>(&Bs[bn][bkg])       = b0;
        *reinterpret_cast<u32x4*>(&Bs[bn][bkg + 8])   = b1;
        __syncthreads();

        bf16x8 af[4], bfr[4];
        #pragma unroll
        for (int i = 0; i < 4; i++)
            af[i] = *reinterpret_cast<const bf16x8*>(&As[wr * 64 + i * 16 + fm][fq * 8]);
        #pragma unroll
        for (int j = 0; j < 4; j++)
            bfr[j] = *reinterpret_cast<const bf16x8*>(&Bs[wc * 64 + j * 16 + fm][fq * 8]);
        #pragma unroll
        for (int i = 0; i < 4; i++)
            #pragma unroll
            for (int j = 0; j < 4; j++)
                acc[i][j] = __builtin_amdgcn_mfma_f32_16x16x32_bf16(af[i], bfr[j], acc[i][j], 0, 0, 0);
    }

    #pragma unroll
    for (int i = 0; i < 4; i++) {
        #pragma unroll
        for (int j = 0; j < 4; j++) {
            int col = n0 + wc * 64 + j * 16 + fm;
            float bb = bias[col];
            if (OUTMODE == 2) {
                int tok = (int)coff + m0 + wr * 64 + i * 16 + fq * 4;
                u32x2 pr = {pk2(acc[i][j][0] + bb, acc[i][j][1] + bb),
                            pk2(acc[i][j][2] + bb, acc[i][j][3] + bb)};
                *reinterpret_cast<u32x2*>(&((u16*)Cv)[(size_t)col * STOT + tok]) = pr;
            } else {
                #pragma unroll
                for (int r = 0; r < 4; r++) {
                    int row = m0 + wr * 64 + i * 16 + fq * 4 + r;
                    size_t idx = coff + (size_t)row * N + col;
                    float val = acc[i][j][r] + bb;
                    if (OUTMODE == 1) ((float*)Cv)[idx] = val;
                    else              ((u16*)Cv)[idx]   = f2b(val);
                }
            }
        }
    }
}

// ---------------------------------------------------------------------------
// Fused per-head RMSNorm + RoPE, in place. 4 waves/block, one token each.
// R8: Q/K bases + row stride are runtime args so the same verified body
// serves both the split layout (Qf,Kf,DIM) and interleaved QK2 (QK2,QK2+3072,
// 6144).
// ---------------------------------------------------------------------------
__global__ __launch_bounds__(256) void rmsrope_kernel(
    u16* __restrict__ Qb, u16* __restrict__ Kb, int qks,
    const float* __restrict__ nq, const float* __restrict__ nk,
    const float* __restrict__ naq, const float* __restrict__ nak,
    const float* __restrict__ cosb, const float* __restrict__ sinb)
{
    const int h     = blockIdx.x;
    const int tok   = blockIdx.y * 4 + (threadIdx.x >> 6);
    const int which = blockIdx.z;
    u16* buf = which ? Kb : Qb;
    const float* nw = (tok < TXT) ? (which ? nak : naq) : (which ? nk : nq);
    const int t = threadIdx.x & 63;
    const size_t base = (size_t)tok * qks + h * HD + 2 * t;

    u32 pr = *reinterpret_cast<const u32*>(&buf[base]);
    float x0 = b2f((u16)(pr & 0xFFFF));
    float x1 = b2f((u16)(pr >> 16));

    float ss = x0 * x0 + x1 * x1;
    #pragma unroll
    for (int off = 32; off; off >>= 1) ss += __shfl_xor(ss, off);
    float r = rsqrtf(ss * (1.0f / 128.0f) + 1e-6f);

    float y0 = x0 * r * nw[2 * t];
    float y1 = x1 * r * nw[2 * t + 1];
    float c0 = cosb[tok * HD + 2 * t];
    float c1 = cosb[tok * HD + 2 * t + 1];
    float s0 = sinb[tok * HD + 2 * t];
    float s1 = sinb[tok * HD + 2 * t + 1];
    float o0 = y0 * c0 - y1 * s0;
    float o1 = y1 * c1 + y0 * s1;
    *reinterpret_cast<u32*>(&buf[base]) = pk2(o0, o1);
}

// ---------------------------------------------------------------------------
// MFMA flash attention (M_rep=2 + XCD chunk swizzle — R6-verified body).
// R8: Q/K bases + row stride are runtime args (Qb,Kb,qks). AO stride stays
// DIM. Swizzle verified: FETCH 164MB -> 23MB.
// ---------------------------------------------------------------------------
__global__ __launch_bounds__(256, 2) void attn_kernel(
    const u16* __restrict__ Qb, const u16* __restrict__ Kb, int qks,
    const u16* __restrict__ VTg, u16* __restrict__ AO)
{
    __shared__ u16 Ks[64][136];
    __shared__ u16 VTs[128][72];
    __shared__ u16 Ps[4][32][72];

    const int t    = threadIdx.x;
    const int w    = t >> 6;
    const int lane = t & 63;
    const int col  = lane & 15;
    const int quad = lane >> 4;

    // XCD-chunked remap: flat dispatch id -> contiguous per-XCD chunk
    const int flat = blockIdx.x + blockIdx.y * 20;      // 480 = 8*60 exact
    const int rm   = (flat & 7) * 60 + (flat >> 3);
    const int h    = rm / 20;
    const int q0   = (rm % 20) * 128;

    const bool is_ref = (q0 >= TXT) && (q0 < TXT + 512);
    const int ks = is_ref ? TXT : 0;
    const int ke = is_ref ? (TXT + 512) : STOT;

    bf16x8 Qfrag[2][4];
    #pragma unroll
    for (int s = 0; s < 2; s++) {
        const size_t qbase = (size_t)(q0 + w * 32 + s * 16 + col) * qks + h * HD;
        #pragma unroll
        for (int c = 0; c < 4; c++)
            Qfrag[s][c] = *reinterpret_cast<const bf16x8*>(&Qb[qbase + c * 32 + quad * 8]);
    }

    f32x4 O[2][8];
    f32x4 m[2], l[2];
    #pragma unroll
    for (int s = 0; s < 2; s++) {
        #pragma unroll
        for (int dt = 0; dt < 8; dt++) O[s][dt] = (f32x4){0.f, 0.f, 0.f, 0.f};
        m[s] = (f32x4){-1e30f, -1e30f, -1e30f, -1e30f};
        l[s] = (f32x4){0.f, 0.f, 0.f, 0.f};
    }

    const int krow = t >> 2, kseg = t & 3;
    const int vrow = t >> 1, vseg = t & 1;

    u32x4 kreg[4], vreg[4];
    {
        const u32x4* src = reinterpret_cast<const u32x4*>(
            &Kb[(size_t)(ks + krow) * qks + h * HD + kseg * 32]);
        kreg[0] = src[0]; kreg[1] = src[1]; kreg[2] = src[2]; kreg[3] = src[3];
        const u32x4* vsrc = reinterpret_cast<const u32x4*>(
            &VTg[(size_t)(h * HD + vrow) * STOT + ks + vseg * 32]);
        vreg[0] = vsrc[0]; vreg[1] = vsrc[1]; vreg[2] = vsrc[2]; vreg[3] = vsrc[3];
    }

    for (int k0 = ks; k0 < ke; k0 += 64) {
        __syncthreads();
        {
            u32x4* dst = reinterpret_cast<u32x4*>(&Ks[krow][kseg * 32]);
            dst[0] = kreg[0]; dst[1] = kreg[1]; dst[2] = kreg[2]; dst[3] = kreg[3];
            u32x4* vdst = reinterpret_cast<u32x4*>(&VTs[vrow][vseg * 32]);
            vdst[0] = vreg[0]; vdst[1] = vreg[1]; vdst[2] = vreg[2]; vdst[3] = vreg[3];
        }
        __syncthreads();

        if (k0 + 64 < ke) {
            const u32x4* src = reinterpret_cast<const u32x4*>(
                &Kb[(size_t)(k0 + 64 + krow) * qks + h * HD + kseg * 32]);
            kreg[0] = src[0]; kreg[1] = src[1]; kreg[2] = src[2]; kreg[3] = src[3];
            const u32x4* vsrc = reinterpret_cast<const u32x4*>(
                &VTg[(size_t)(h * HD + vrow) * STOT + k0 + 64 + vseg * 32]);
            vreg[0] = vsrc[0]; vreg[1] = vsrc[1]; vreg[2] = vsrc[2]; vreg[3] = vsrc[3];
        }

        f32x4 sc[2][4];
        #pragma unroll
        for (int kt = 0; kt < 4; kt++) {
            f32x4 a0 = (f32x4){0.f, 0.f, 0.f, 0.f};
            f32x4 a1 = (f32x4){0.f, 0.f, 0.f, 0.f};
            #pragma unroll
            for (int c = 0; c < 4; c++) {
                bf16x8 kf = *reinterpret_cast<const bf16x8*>(
                    &Ks[kt * 16 + col][c * 32 + quad * 8]);
                a0 = __builtin_amdgcn_mfma_f32_16x16x32_bf16(Qfrag[0][c], kf, a0, 0, 0, 0);
                a1 = __builtin_amdgcn_mfma_f32_16x16x32_bf16(Qfrag[1][c], kf, a1, 0, 0, 0);
            }
            sc[0][kt] = a0 * SOFTMAX_SCALE;
            sc[1][kt] = a1 * SOFTMAX_SCALE;
        }

        #pragma unroll
        for (int s = 0; s < 2; s++) {
            f32x4 tmax = max4(max4(sc[s][0], sc[s][1]), max4(sc[s][2], sc[s][3]));
            tmax = max4(tmax, shfl_xor4(tmax, 1));
            tmax = max4(tmax, shfl_xor4(tmax, 2));
            tmax = max4(tmax, shfl_xor4(tmax, 4));
            tmax = max4(tmax, shfl_xor4(tmax, 8));
            const bool ok = (tmax[0] - m[s][0] <= 8.0f) && (tmax[1] - m[s][1] <= 8.0f) &&
                            (tmax[2] - m[s][2] <= 8.0f) && (tmax[3] - m[s][3] <= 8.0f);
            const bool skip = __all(ok);
            f32x4 mnew = skip ? m[s] : max4(m[s], tmax);

            f32x4 rowsum = (f32x4){0.f, 0.f, 0.f, 0.f};
            f32x4 p[4];
            #pragma unroll
            for (int kt = 0; kt < 4; kt++)
                #pragma unroll
                for (int r = 0; r < 4; r++) {
                    p[kt][r] = __expf(sc[s][kt][r] - mnew[r]);
                    rowsum[r] += p[kt][r];
                }
            rowsum += shfl_xor4(rowsum, 1);
            rowsum += shfl_xor4(rowsum, 2);
            rowsum += shfl_xor4(rowsum, 4);
            rowsum += shfl_xor4(rowsum, 8);

            if (skip) {
                #pragma unroll
                for (int r = 0; r < 4; r++) l[s][r] += rowsum[r];
            } else {
                f32x4 alpha;
                #pragma unroll
                for (int r = 0; r < 4; r++) alpha[r] = __expf(m[s][r] - mnew[r]);
                #pragma unroll
                for (int r = 0; r < 4; r++) l[s][r] = l[s][r] * alpha[r] + rowsum[r];
                m[s] = mnew;
                #pragma unroll
                for (int dt = 0; dt < 8; dt++)
                    #pragma unroll
                    for (int r = 0; r < 4; r++) O[s][dt][r] *= alpha[r];
            }

            #pragma unroll
            for (int r = 0; r < 4; r++) {
                u32 w01 = pk2(p[0][r], p[1][r]);
                u32 w23 = pk2(p[2][r], p[3][r]);
                u16* prow = &Ps[w][s * 16 + quad * 4 + r][0];
                prow[col]      = (u16)(w01 & 0xFFFFu);
                prow[col + 16] = (u16)(w01 >> 16);
                prow[col + 32] = (u16)(w23 & 0xFFFFu);
                prow[col + 48] = (u16)(w23 >> 16);
            }
        }

        __builtin_amdgcn_s_setprio(1);
        #pragma unroll
        for (int c = 0; c < 2; c++) {
            bf16x8 pf0 = *reinterpret_cast<const bf16x8*>(
                &Ps[w][col][c * 32 + quad * 8]);
            bf16x8 pf1 = *reinterpret_cast<const bf16x8*>(
                &Ps[w][16 + col][c * 32 + quad * 8]);
            #pragma unroll
            for (int dt = 0; dt < 8; dt++) {
                bf16x8 vf = *reinterpret_cast<const bf16x8*>(
                    &VTs[dt * 16 + col][c * 32 + quad * 8]);
                O[0][dt] = __builtin_amdgcn_mfma_f32_16x16x32_bf16(pf0, vf, O[0][dt], 0, 0, 0);
                O[1][dt] = __builtin_amdgcn_mfma_f32_16x16x32_bf16(pf1, vf, O[1][dt], 0, 0, 0);
            }
        }
        __builtin_amdgcn_s_setprio(0);
    }

    #pragma unroll
    for (int s = 0; s < 2; s++) {
        f32x4 inv;
        #pragma unroll
        for (int r = 0; r < 4; r++) inv[r] = 1.0f / l[s][r];
        #pragma unroll
        for (int dt = 0; dt < 8; dt++)
            #pragma unroll
            for (int r = 0; r < 4; r++)
                AO[(size_t)(q0 + w * 32 + s * 16 + quad * 4 + r) * DIM + h * HD + dt * 16 + col] =
                    f2b(O[s][dt][r] * inv[r]);
    }
}

// ---------------------------------------------------------------------------
// Tier A' (ws >= 88,080,384 — PROVEN available by R7 executing Tier A):
//   ws:    QK2  [0, 31,457,280)           bf16 [STOT][6144] interleaved Q|K
//          WT2  [31,457,280, 69,206,016)  bf16 [6144][3072] two transposed Ws
//          AO   [69,206,016, 84,934,656)  bf16 [STOT][3072]
//          bQK  [84,934,656, +24,576)     f32 [bq|bk]
//          bQKa [84,959,232, +24,576)     f32 [baq|bak]
//   d_out: VTg  [0, 15,728,640)           bf16 [3072][2560]
//          Xbf  [15,728,640, 31,457,280)  bf16 [STOT][3072] input copy
//   Only verified kernel binaries; merged-QK via gemm_bt2 ARGUMENTS
//   (grid (M/MT,48), Ntot=6144) -> 768-block grid, 3 blocks/CU.
// Tier B: R6-verified path, unchanged.
// ---------------------------------------------------------------------------
extern "C" void kernel_launch(void* const* d_in, const int* in_sizes, int n_in,
                              void* d_out, int out_size, void* d_ws, size_t ws_size,
                              hipStream_t stream)
{
    const void*  hs  = d_in[0];
    const void*  enc = d_in[1];
    const float* rc  = (const float*)d_in[2];
    const float* rs  = (const float*)d_in[3];
    const float* wq  = (const float*)d_in[4];  const float* bq  = (const float*)d_in[5];
    const float* wk  = (const float*)d_in[6];  const float* bk  = (const float*)d_in[7];
    const float* wv  = (const float*)d_in[8];  const float* bv  = (const float*)d_in[9];
    const float* waq = (const float*)d_in[10]; const float* baq = (const float*)d_in[11];
    const float* wak = (const float*)d_in[12]; const float* bak = (const float*)d_in[13];
    const float* wav = (const float*)d_in[14]; const float* bav = (const float*)d_in[15];
    const float* nq  = (const float*)d_in[16]; const float* nk  = (const float*)d_in[17];
    const float* naq = (const float*)d_in[18]; const float* nak = (const float*)d_in[19];
    const float* wo  = (const float*)d_in[20]; const float* bo  = (const float*)d_in[21];
    const float* wao = (const float*)d_in[22]; const float* bao = (const float*)d_in[23];

    const size_t QFB = (size_t)STOT * DIM * sizeof(u16);      // 15,728,640
    const size_t WTF = (size_t)DIM * DIM * sizeof(u16);       // 18,874,368
    const size_t DD  = (size_t)DIM * DIM;

    dim3 blk(256);
    dim3 tgrid(DIM / 64, DIM / 64);

    if (ws_size >= 2 * QFB + 3 * WTF) {
        // ---- Tier A': merged-QK via verified gemm_bt2, interleaved layout ----
        u16*   QK2  = (u16*)d_ws;
        u16*   WT2  = (u16*)((char*)d_ws + 31457280);
        u16*   AOa  = (u16*)((char*)d_ws + 69206016);
        float* bQK  = (float*)((char*)d_ws + 84934656);
        float* bQKa = (float*)((char*)d_ws + 84959232);
        u16*   VTg  = (u16*)d_out;
        u16*   Xbf  = (u16*)d_out + (size_t)STOT * DIM;

        convert_bf16_kernel<<<dim3((SEQ * DIM / 8) / 256), blk, 0, stream>>>(
            (const float*)hs, Xbf + (size_t)TXT * DIM, SEQ * DIM / 8);
        convert_bf16_kernel<<<dim3((TXT * DIM / 8) / 256), blk, 0, stream>>>(
            (const float*)enc, Xbf, TXT * DIM / 8);
        hipMemcpyAsync(bQK,         bq,  DIM * sizeof(float), hipMemcpyDeviceToDevice, stream);
        hipMemcpyAsync(bQK + DIM,   bk,  DIM * sizeof(float), hipMemcpyDeviceToDevice, stream);
        hipMemcpyAsync(bQKa,        baq, DIM * sizeof(float), hipMemcpyDeviceToDevice, stream);
        hipMemcpyAsync(bQKa + DIM,  bak, DIM * sizeof(float), hipMemcpyDeviceToDevice, stream);

        // QK projections (merged): hs then enc
        transpose_w_kernel<<<tgrid, blk, 0, stream>>>(wq, WT2,      DIM, DIM, 0);
        transpose_w_kernel<<<tgrid, blk, 0, stream>>>(wk, WT2 + DD, DIM, DIM, 0);
        gemm_bt2_kernel<0, 128><<<dim3(SEQ / 128, 2 * DIM / 128), blk, 0, stream>>>(
            Xbf + (size_t)TXT * DIM, WT2, bQK, QK2, (size_t)TXT * 2 * DIM, DIM, 2 * DIM, 0);
        transpose_w_kernel<<<tgrid, blk, 0, stream>>>(waq, WT2,      DIM, DIM, 0);
        transpose_w_kernel<<<tgrid, blk, 0, stream>>>(wak, WT2 + DD, DIM, DIM, 0);
        gemm_bt2_kernel<0, 64><<<dim3(TXT / 64, 2 * DIM / 128), blk, 0, stream>>>(
            Xbf, WT2, bQKa, QK2, 0, DIM, 2 * DIM, 0);

        // V projections (transposed output)
        transpose_w_kernel<<<tgrid, blk, 0, stream>>>(wv,  WT2,      DIM, DIM, 0);
        transpose_w_kernel<<<tgrid, blk, 0, stream>>>(wav, WT2 + DD, DIM, DIM, 0);
        gemm_bt2_kernel<2, 128><<<dim3(SEQ / 128, DIM / 128), blk, 0, stream>>>(
            Xbf + (size_t)TXT * DIM, WT2,      bv,  VTg, (size_t)TXT, DIM, DIM, 0);
        gemm_bt2_kernel<2, 64><<<dim3(TXT / 64, DIM / 128), blk, 0, stream>>>(
            Xbf,                     WT2 + DD, bav, VTg, 0,           DIM, DIM, 0);

        rmsrope_kernel<<<dim3(NH, STOT / 4, 2), blk, 0, stream>>>(
            QK2, QK2 + DIM, 2 * DIM, nq, nk, naq, nak, rc, rs);
        attn_kernel<<<dim3(STOT / 128, NH), blk, 0, stream>>>(
            QK2, QK2 + DIM, 2 * DIM, VTg, AOa);

        // output projections (overwrite d_out; VTg/Xbf dead)
        transpose_w_kernel<<<tgrid, blk, 0, stream>>>(wo,  WT2,      DIM, DIM, 0);
        transpose_w_kernel<<<tgrid, blk, 0, stream>>>(wao, WT2 + DD, DIM, DIM, 0);
        gemm_bt2_kernel<1, 128><<<dim3(SEQ / 128, DIM / 128), blk, 0, stream>>>(
            AOa + (size_t)TXT * DIM, WT2,      bo,  d_out, 0,                 DIM, DIM, 0);
        gemm_bt2_kernel<1, 64><<<dim3(TXT / 64, DIM / 128), blk, 0, stream>>>(
            AOa,                     WT2 + DD, bao, d_out, (size_t)SEQ * DIM, DIM, DIM, 0);
        return;
    }

    u16* Qf  = (u16*)d_ws;
    u16* Kf  = (u16*)d_out;
    u16* VTg = (u16*)d_out + (size_t)STOT * DIM;
    u16* AO  = Qf;

    if (ws_size >= 2 * QFB + WTF) {
        // ---- Tier B: R6 verified path (per-weight GEMMs) ----
        u16* WT  = (u16*)((char*)d_ws + QFB);
        u16* Xbf = (u16*)((char*)d_ws + QFB + WTF);
        convert_bf16_kernel<<<dim3((SEQ * DIM / 8) / 256), blk, 0, stream>>>(
            (const float*)hs, Xbf + (size_t)TXT * DIM, SEQ * DIM / 8);
        convert_bf16_kernel<<<dim3((TXT * DIM / 8) / 256), blk, 0, stream>>>(
            (const float*)enc, Xbf, TXT * DIM / 8);
        #define RUN2(MODE_, MT_, Aptr, Wptr, Bias, Cptr, Coff, M_)                   \
            transpose_w_kernel<<<tgrid, blk, 0, stream>>>(Wptr, WT, DIM, DIM, 0);    \
            gemm_bt2_kernel<MODE_, MT_><<<dim3((M_) / MT_, DIM / 128), blk, 0, stream>>>( \
                Aptr, WT, Bias, Cptr, Coff, DIM, DIM, 0);
        RUN2(0, 128, Xbf + (size_t)TXT * DIM, wq,  bq,  Qf,  (size_t)TXT * DIM, SEQ)
        RUN2(0, 128, Xbf + (size_t)TXT * DIM, wk,  bk,  Kf,  (size_t)TXT * DIM, SEQ)
        RUN2(2, 128, Xbf + (size_t)TXT * DIM, wv,  bv,  VTg, (size_t)TXT,       SEQ)
        RUN2(0, 64,  Xbf,                     waq, baq, Qf,  0,                 TXT)
        RUN2(0, 64,  Xbf,                     wak, bak, Kf,  0,                 TXT)
        RUN2(2, 64,  Xbf,                     wav, bav, VTg, 0,                 TXT)
        rmsrope_kernel<<<dim3(NH, STOT / 4, 2), blk, 0, stream>>>(Qf, Kf, DIM, nq, nk, naq, nak, rc, rs);
        attn_kernel<<<dim3(STOT / 128, NH), blk, 0, stream>>>(Qf, Kf, DIM, VTg, AO);
        RUN2(1, 128, AO + (size_t)TXT * DIM, wo,  bo,  d_out, 0,                 SEQ)
        RUN2(1, 64,  AO,                     wao, bao, d_out, (size_t)SEQ * DIM, TXT)
        #undef RUN2
        return;
    }

    int nchunk;
    if      (ws_size >= QFB + WTF)     nchunk = DIM;
    else if (ws_size >= QFB + WTF / 2) nchunk = DIM / 2;
    else                               nchunk = 0;

    if (nchunk > 0) {
        u16* WT = (u16*)((char*)d_ws + QFB);
        dim3 tgrid2(DIM / 64, nchunk / 64);
        #define RUN_GEMM(AF32_, MODE_, MT_, Aptr, Wptr, Bias, Cptr, Coff, M_)     \
            for (int nb = 0; nb < DIM; nb += nchunk) {                            \
                transpose_w_kernel<<<tgrid2, blk, 0, stream>>>(Wptr, WT, DIM, DIM, nb); \
                gemm_bt_kernel<AF32_, MODE_, MT_><<<dim3((M_) / MT_, nchunk / 128), blk, 0, stream>>>( \
                    Aptr, WT, Bias, Cptr, Coff, M_, DIM, DIM, nb);                \
            }
        RUN_GEMM(1, 0, 128, hs,  wq,  bq,  Qf,  (size_t)TXT * DIM, SEQ)
        RUN_GEMM(1, 0, 128, hs,  wk,  bk,  Kf,  (size_t)TXT * DIM, SEQ)
        RUN_GEMM(1, 2, 128, hs,  wv,  bv,  VTg, (size_t)TXT,       SEQ)
        RUN_GEMM(1, 0, 64,  enc, waq, baq, Qf,  0,                 TXT)
        RUN_GEMM(1, 0, 64,  enc, wak, bak, Kf,  0,                 TXT)
        RUN_GEMM(1, 2, 64,  enc, wav, bav, VTg, 0,                 TXT)
        rmsrope_kernel<<<dim3(NH, STOT / 4, 2), blk, 0, stream>>>(Qf, Kf, DIM, nq, nk, naq, nak, rc, rs);
        attn_kernel<<<dim3(STOT / 128, NH), blk, 0, stream>>>(Qf, Kf, DIM, VTg, AO);
        RUN_GEMM(0, 1, 128, AO + (size_t)TXT * DIM, wo,  bo,  d_out, 0,                 SEQ)
        RUN_GEMM(0, 1, 64,  AO,                     wao, bao, d_out, (size_t)SEQ * DIM, TXT)
        #undef RUN_GEMM
    } else {
        gemm_bias_kernel<1,0><<<dim3(SEQ / 128, DIM / 128), blk, 0, stream>>>(hs, wq, bq, Qf, (size_t)TXT * DIM, SEQ, DIM, DIM);
        gemm_bias_kernel<1,0><<<dim3(SEQ / 128, DIM / 128), blk, 0, stream>>>(hs, wk, bk, Kf, (size_t)TXT * DIM, SEQ, DIM, DIM);
        gemm_bias_kernel<1,2><<<dim3(SEQ / 128, DIM / 128), blk, 0, stream>>>(hs, wv, bv, VTg, (size_t)TXT, SEQ, DIM, DIM);
        gemm_bias_kernel<1,0><<<dim3(TXT / 128, DIM / 128), blk, 0, stream>>>(enc, waq, baq, Qf, 0, TXT, DIM, DIM);
        gemm_bias_kernel<1,0><<<dim3(TXT / 128, DIM / 128), blk, 0, stream>>>(enc, wak, bak, Kf, 0, TXT, DIM, DIM);
        gemm_bias_kernel<1,2><<<dim3(TXT / 128, DIM / 128), blk, 0, stream>>>(enc, wav, bav, VTg, 0, TXT, DIM, DIM);
        rmsrope_kernel<<<dim3(NH, STOT / 4, 2), blk, 0, stream>>>(Qf, Kf, DIM, nq, nk, naq, nak, rc, rs);
        attn_kernel<<<dim3(STOT / 128, NH), blk, 0, stream>>>(Qf, Kf, DIM, VTg, AO);
        gemm_bias_kernel<0,1><<<dim3(SEQ / 128, DIM / 128), blk, 0, stream>>>(AO + (size_t)TXT * DIM, wo, bo, d_out, 0, SEQ, DIM, DIM);
        gemm_bias_kernel<0,1><<<dim3(TXT / 128, DIM / 128), blk, 0, stream>>>(AO, wao, bao, d_out, (size_t)SEQ * DIM, TXT, DIM, DIM);
    }
}